// Round 1
// baseline (692.633 us; speedup 1.0000x reference)
//
#include <hip/hip_runtime.h>
#include <float.h>
#include <math.h>

// Problem constants
constexpr int B_ = 64, S_ = 512, N_ = 128, D_ = 768;
// GEMM tiling
constexpr int BM = 128, BN = 128, BK = 16;

// ---------------------------------------------------------------------------
// tmps[b,n,:] = sum_{r=s+1..e} sentence_embed[b,r,:]   (torch slice [s+1:e+1])
__global__ __launch_bounds__(192)
void span_sum_kernel(const float* __restrict__ se, const int* __restrict__ spans,
                     float* __restrict__ tmps) {
    const int bn = blockIdx.x;             // b*N + n
    const int b  = bn >> 7;                // N_ = 128
    const int s  = spans[bn * 2 + 0];
    const int e  = spans[bn * 2 + 1];
    const float* base = se + (size_t)b * S_ * D_;
    const int d4 = threadIdx.x;            // 192 threads * float4 = 768
    float4 acc = make_float4(0.f, 0.f, 0.f, 0.f);
    for (int r = s + 1; r <= e; ++r) {
        const float4 v = reinterpret_cast<const float4*>(base + (size_t)r * D_)[d4];
        acc.x += v.x; acc.y += v.y; acc.z += v.z; acc.w += v.w;
    }
    reinterpret_cast<float4*>(tmps + (size_t)bn * D_)[d4] = acc;
}

// ---------------------------------------------------------------------------
// target_max[b,:] = max over rows [s,e) of sentence_embed[b]
__global__ __launch_bounds__(192)
void target_max_kernel(const float* __restrict__ se, const int* __restrict__ tspan,
                       float* __restrict__ tmax) {
    const int b = blockIdx.x;
    const int s = tspan[b * 2 + 0];
    const int e = tspan[b * 2 + 1];
    const float* base = se + (size_t)b * S_ * D_;
    const int d4 = threadIdx.x;
    float4 m = make_float4(-FLT_MAX, -FLT_MAX, -FLT_MAX, -FLT_MAX);
    for (int r = s; r < e; ++r) {
        const float4 v = reinterpret_cast<const float4*>(base + (size_t)r * D_)[d4];
        m.x = fmaxf(m.x, v.x); m.y = fmaxf(m.y, v.y);
        m.z = fmaxf(m.z, v.z); m.w = fmaxf(m.w, v.w);
    }
    reinterpret_cast<float4*>(tmax + (size_t)b * D_)[d4] = m;
}

// ---------------------------------------------------------------------------
// adj = clamp(dg+dg1, max 1); invden[row] = 1/(rowsum + 1e-7)
__global__ __launch_bounds__(128)
void adj_kernel(const float* __restrict__ dg, const float* __restrict__ dg1,
                float* __restrict__ adj, float* __restrict__ invden) {
    const int row = blockIdx.x;            // b*N + n
    const int t   = threadIdx.x;           // 128
    const size_t idx = (size_t)row * N_ + t;
    float a = dg[idx] + dg1[idx];
    a = (a >= 1.f) ? 1.f : a;
    adj[idx] = a;
    float w = a;
    #pragma unroll
    for (int off = 32; off; off >>= 1) w += __shfl_down(w, off, 64);
    __shared__ float ssum[2];
    if ((t & 63) == 0) ssum[t >> 6] = w;
    __syncthreads();
    if (t == 0) invden[row] = 1.f / (ssum[0] + ssum[1] + 1e-7f);
}

// ---------------------------------------------------------------------------
// C[M,Nn] = A[M,K] @ Bm[K,Nn], optional relu. Sizes divisible by tiles.
template<int RELU>
__global__ __launch_bounds__(256)
void gemm_nn(const float* __restrict__ A, const float* __restrict__ Bm,
             float* __restrict__ C, int M, int Nn, int K) {
    __shared__ float As[BK][BM + 4];
    __shared__ float Bs[BK][BN + 4];
    const int tid = threadIdx.x;
    const int bm = blockIdx.y * BM;
    const int bn = blockIdx.x * BN;
    const int tx = tid & 15;
    const int ty = tid >> 4;

    const int a_m = tid >> 1;              // 0..127
    const int a_k = (tid & 1) * 8;         // 0 or 8
    const int b_k = tid >> 4;              // 0..15
    const int b_n = (tid & 15) * 8;        // 0..120

    const float* Aptr = A + (size_t)(bm + a_m) * K + a_k;
    const float* Bptr = Bm + (size_t)b_k * Nn + bn + b_n;

    float acc[8][8];
    #pragma unroll
    for (int i = 0; i < 8; ++i)
        #pragma unroll
        for (int j = 0; j < 8; ++j) acc[i][j] = 0.f;

    for (int k0 = 0; k0 < K; k0 += BK) {
        const float4 a0 = *reinterpret_cast<const float4*>(Aptr);
        const float4 a1 = *reinterpret_cast<const float4*>(Aptr + 4);
        const float4 b0 = *reinterpret_cast<const float4*>(Bptr);
        const float4 b1 = *reinterpret_cast<const float4*>(Bptr + 4);
        __syncthreads();
        As[a_k + 0][a_m] = a0.x; As[a_k + 1][a_m] = a0.y;
        As[a_k + 2][a_m] = a0.z; As[a_k + 3][a_m] = a0.w;
        As[a_k + 4][a_m] = a1.x; As[a_k + 5][a_m] = a1.y;
        As[a_k + 6][a_m] = a1.z; As[a_k + 7][a_m] = a1.w;
        *reinterpret_cast<float4*>(&Bs[b_k][b_n])     = b0;
        *reinterpret_cast<float4*>(&Bs[b_k][b_n + 4]) = b1;
        __syncthreads();
        #pragma unroll
        for (int k = 0; k < BK; ++k) {
            const float4 av0 = *reinterpret_cast<const float4*>(&As[k][ty * 8]);
            const float4 av1 = *reinterpret_cast<const float4*>(&As[k][ty * 8 + 4]);
            const float4 bv0 = *reinterpret_cast<const float4*>(&Bs[k][tx * 8]);
            const float4 bv1 = *reinterpret_cast<const float4*>(&Bs[k][tx * 8 + 4]);
            const float ar[8] = {av0.x, av0.y, av0.z, av0.w, av1.x, av1.y, av1.z, av1.w};
            const float br[8] = {bv0.x, bv0.y, bv0.z, bv0.w, bv1.x, bv1.y, bv1.z, bv1.w};
            #pragma unroll
            for (int i = 0; i < 8; ++i)
                #pragma unroll
                for (int j = 0; j < 8; ++j)
                    acc[i][j] = fmaf(ar[i], br[j], acc[i][j]);
        }
        Aptr += BK;
        Bptr += (size_t)BK * Nn;
    }
    #pragma unroll
    for (int i = 0; i < 8; ++i) {
        const int row = bm + ty * 8 + i;
        float* crow = C + (size_t)row * Nn + bn + tx * 8;
        float o[8];
        #pragma unroll
        for (int j = 0; j < 8; ++j)
            o[j] = RELU ? fmaxf(acc[i][j], 0.f) : acc[i][j];
        *reinterpret_cast<float4*>(crow)     = make_float4(o[0], o[1], o[2], o[3]);
        *reinterpret_cast<float4*>(crow + 4) = make_float4(o[4], o[5], o[6], o[7]);
    }
}

// ---------------------------------------------------------------------------
// Per-batch: x = relu( (adj[b] @ hW[b]) * invden[b,row] + bias ) + x
// M = K = 128 (= N_), Nn = 768 (= D_). blockIdx.z = batch.
__global__ __launch_bounds__(256)
void adj_gemm(const float* __restrict__ adjA, const float* __restrict__ hW,
              const float* __restrict__ invden, const float* __restrict__ bias,
              float* __restrict__ x) {
    __shared__ float As[BK][BM + 4];
    __shared__ float Bs[BK][BN + 4];
    const int b   = blockIdx.z;
    const int tid = threadIdx.x;
    const int bn  = blockIdx.x * BN;
    const int tx = tid & 15;
    const int ty = tid >> 4;

    const float* A  = adjA + (size_t)b * N_ * N_;
    const float* Bm = hW   + (size_t)b * N_ * D_;
    float* X        = x    + (size_t)b * N_ * D_;

    const int a_m = tid >> 1;
    const int a_k = (tid & 1) * 8;
    const int b_k = tid >> 4;
    const int b_n = (tid & 15) * 8;

    const float* Aptr = A + (size_t)a_m * N_ + a_k;
    const float* Bptr = Bm + (size_t)b_k * D_ + bn + b_n;

    float acc[8][8];
    #pragma unroll
    for (int i = 0; i < 8; ++i)
        #pragma unroll
        for (int j = 0; j < 8; ++j) acc[i][j] = 0.f;

    for (int k0 = 0; k0 < N_; k0 += BK) {
        const float4 a0 = *reinterpret_cast<const float4*>(Aptr);
        const float4 a1 = *reinterpret_cast<const float4*>(Aptr + 4);
        const float4 b0 = *reinterpret_cast<const float4*>(Bptr);
        const float4 b1 = *reinterpret_cast<const float4*>(Bptr + 4);
        __syncthreads();
        As[a_k + 0][a_m] = a0.x; As[a_k + 1][a_m] = a0.y;
        As[a_k + 2][a_m] = a0.z; As[a_k + 3][a_m] = a0.w;
        As[a_k + 4][a_m] = a1.x; As[a_k + 5][a_m] = a1.y;
        As[a_k + 6][a_m] = a1.z; As[a_k + 7][a_m] = a1.w;
        *reinterpret_cast<float4*>(&Bs[b_k][b_n])     = b0;
        *reinterpret_cast<float4*>(&Bs[b_k][b_n + 4]) = b1;
        __syncthreads();
        #pragma unroll
        for (int k = 0; k < BK; ++k) {
            const float4 av0 = *reinterpret_cast<const float4*>(&As[k][ty * 8]);
            const float4 av1 = *reinterpret_cast<const float4*>(&As[k][ty * 8 + 4]);
            const float4 bv0 = *reinterpret_cast<const float4*>(&Bs[k][tx * 8]);
            const float4 bv1 = *reinterpret_cast<const float4*>(&Bs[k][tx * 8 + 4]);
            const float ar[8] = {av0.x, av0.y, av0.z, av0.w, av1.x, av1.y, av1.z, av1.w};
            const float br[8] = {bv0.x, bv0.y, bv0.z, bv0.w, bv1.x, bv1.y, bv1.z, bv1.w};
            #pragma unroll
            for (int i = 0; i < 8; ++i)
                #pragma unroll
                for (int j = 0; j < 8; ++j)
                    acc[i][j] = fmaf(ar[i], br[j], acc[i][j]);
        }
        Aptr += BK;
        Bptr += (size_t)BK * D_;
    }
    #pragma unroll
    for (int i = 0; i < 8; ++i) {
        const int row = ty * 8 + i;
        const float inv = invden[b * N_ + row];
        float* xrow = X + (size_t)row * D_ + bn + tx * 8;
        float o[8];
        #pragma unroll
        for (int j = 0; j < 8; ++j) {
            const float v = fmaxf(acc[i][j] * inv + bias[bn + tx * 8 + j], 0.f);
            o[j] = v + xrow[j];
        }
        *reinterpret_cast<float4*>(xrow)     = make_float4(o[0], o[1], o[2], o[3]);
        *reinterpret_cast<float4*>(xrow + 4) = make_float4(o[4], o[5], o[6], o[7]);
    }
}

// ---------------------------------------------------------------------------
// gcn_target[b,:] = sum over nodes [gs,ge) of x[b,n,:]
__global__ __launch_bounds__(192)
void gcn_target_kernel(const float* __restrict__ x, const int* __restrict__ gspan,
                       float* __restrict__ gt) {
    const int b = blockIdx.x;
    const int s = gspan[b * 2 + 0];
    const int e = gspan[b * 2 + 1];
    const float* base = x + (size_t)b * N_ * D_;
    const int d4 = threadIdx.x;
    float4 acc = make_float4(0.f, 0.f, 0.f, 0.f);
    for (int n = s; n < e; ++n) {
        const float4 v = reinterpret_cast<const float4*>(base + (size_t)n * D_)[d4];
        acc.x += v.x; acc.y += v.y; acc.z += v.z; acc.w += v.w;
    }
    reinterpret_cast<float4*>(gt + (size_t)b * D_)[d4] = acc;
}

// ---------------------------------------------------------------------------
// logits[b,o] = tanh( concat(tmax, gt)[b,:] @ fcW + fcb )
__global__ __launch_bounds__(256)
void head_kernel(const float* __restrict__ tmax, const float* __restrict__ gt,
                 const float* __restrict__ fcW, const float* __restrict__ fcb,
                 float* __restrict__ out) {
    const int b = blockIdx.x;
    const int t = threadIdx.x;
    float p0 = 0.f, p1 = 0.f, p2 = 0.f;
    for (int i = t; i < 2 * D_; i += 256) {
        const float v = (i < D_) ? tmax[(size_t)b * D_ + i] : gt[(size_t)b * D_ + i - D_];
        p0 += v * fcW[i * 3 + 0];
        p1 += v * fcW[i * 3 + 1];
        p2 += v * fcW[i * 3 + 2];
    }
    #pragma unroll
    for (int off = 32; off; off >>= 1) {
        p0 += __shfl_down(p0, off, 64);
        p1 += __shfl_down(p1, off, 64);
        p2 += __shfl_down(p2, off, 64);
    }
    __shared__ float red[4][3];
    const int wv = t >> 6;
    if ((t & 63) == 0) { red[wv][0] = p0; red[wv][1] = p1; red[wv][2] = p2; }
    __syncthreads();
    if (t == 0) {
        #pragma unroll
        for (int o = 0; o < 3; ++o) {
            const float s = red[0][o] + red[1][o] + red[2][o] + red[3][o] + fcb[o];
            out[b * 3 + o] = tanhf(s);
        }
    }
}

// ---------------------------------------------------------------------------
extern "C" void kernel_launch(void* const* d_in, const int* in_sizes, int n_in,
                              void* d_out, int out_size, void* d_ws, size_t ws_size,
                              hipStream_t stream) {
    const float* se   = (const float*)d_in[0];
    const float* dg   = (const float*)d_in[1];
    const float* dg1  = (const float*)d_in[2];
    const float* Wp   = (const float*)d_in[3];
    const float* Wg[3]  = {(const float*)d_in[4], (const float*)d_in[6], (const float*)d_in[8]};
    const float* bg[3]  = {(const float*)d_in[5], (const float*)d_in[7], (const float*)d_in[9]};
    const float* fcW  = (const float*)d_in[10];
    const float* fcb  = (const float*)d_in[11];
    const int*   tspan  = (const int*)d_in[12];
    const int*   nspans = (const int*)d_in[13];
    const int*   gspan  = (const int*)d_in[14];
    float* out = (float*)d_out;

    // workspace layout (floats)
    float* X   = (float*)d_ws;                       // B*N*D = 6291456
    float* HW  = X   + (size_t)B_ * N_ * D_;         // B*N*D (tmps, then per-layer hW)
    float* ADJ = HW  + (size_t)B_ * N_ * D_;         // B*N*N = 1048576
    float* INV = ADJ + (size_t)B_ * N_ * N_;         // B*N
    float* TMX = INV + (size_t)B_ * N_;              // B*D
    float* GT  = TMX + (size_t)B_ * D_;              // B*D

    // Stage A: ragged span sums + target max + adjacency
    span_sum_kernel<<<B_ * N_, 192, 0, stream>>>(se, nspans, HW);
    target_max_kernel<<<B_, 192, 0, stream>>>(se, tspan, TMX);
    adj_kernel<<<B_ * N_, 128, 0, stream>>>(dg, dg1, ADJ, INV);

    // Stage B: x = relu(tmps @ W_proj)
    dim3 gemm_grid(D_ / BN, (B_ * N_) / BM);         // (6, 64)
    gemm_nn<1><<<gemm_grid, 256, 0, stream>>>(HW, Wp, X, B_ * N_, D_, D_);

    // Stage C: 3 GCN layers
    dim3 adj_grid(D_ / BN, 1, B_);                   // (6, 1, 64)
    for (int l = 0; l < 3; ++l) {
        gemm_nn<0><<<gemm_grid, 256, 0, stream>>>(X, Wg[l], HW, B_ * N_, D_, D_);
        adj_gemm<<<adj_grid, 256, 0, stream>>>(ADJ, HW, INV, bg[l], X);
    }

    // Stage D: ragged node-span sum + head
    gcn_target_kernel<<<B_, 192, 0, stream>>>(X, gspan, GT);
    head_kernel<<<B_, 256, 0, stream>>>(TMX, GT, fcW, fcb, out);
}

// Round 2
// 346.960 us; speedup vs baseline: 1.9963x; 1.9963x over previous
//
#include <hip/hip_runtime.h>
#include <float.h>
#include <math.h>

typedef __attribute__((ext_vector_type(8))) short short8;
typedef __attribute__((ext_vector_type(4))) float f32x4;
typedef __attribute__((ext_vector_type(4))) unsigned short u16x4;
typedef unsigned short u16;
typedef unsigned int u32;

constexpr int B_ = 64, S_ = 512, N_ = 128, D_ = 768;

// ---------------------------------------------------------------------------
__device__ inline u16 bf16_rne(float x) {
    u32 u = __builtin_bit_cast(u32, x);
    u += 0x7FFFu + ((u >> 16) & 1u);
    return (u16)(u >> 16);
}
__device__ inline float bf2f(u16 h) {
    u32 u = ((u32)h) << 16;
    return __builtin_bit_cast(float, u);
}
__device__ inline void split2(float x, u16& h, u16& l) {
    h = bf16_rne(x);
    l = bf16_rne(x - bf2f(h));
}

__device__ inline void gload_lds16(const u16* g, u16* s) {
    __builtin_amdgcn_global_load_lds(
        (const __attribute__((address_space(1))) u32*)g,
        (__attribute__((address_space(3))) u32*)s, 16, 0, 0);
}

// stage a 128-row x 32-elem bf16 tile (row length 64 B) into linear LDS.
// g points at (row0, k0); rowStride in elements. One wave: 8 instructions.
__device__ inline void stage_tile(const u16* g, u16* s, int lane, int rowStride) {
    const u16* gb = g + (size_t)(lane >> 2) * rowStride + (size_t)(lane & 3) * 8;
    #pragma unroll
    for (int i = 0; i < 8; ++i)
        gload_lds16(gb + (size_t)(i * 16) * rowStride, s + i * 512);
}

// ---------------------------------------------------------------------------
// tmps[b,n,:] = sum_{r=s+1..e} se[b,r,:]  -> split bf16 hi/lo
__global__ __launch_bounds__(192)
void span_split_kernel(const float* __restrict__ se, const int* __restrict__ spans,
                       u16* __restrict__ th, u16* __restrict__ tl) {
    const int bn = blockIdx.x;
    const int b  = bn >> 7;
    const int s  = spans[bn * 2 + 0];
    const int e  = spans[bn * 2 + 1];
    const float* base = se + (size_t)b * S_ * D_;
    const int d4 = threadIdx.x;
    float4 acc = make_float4(0.f, 0.f, 0.f, 0.f);
    for (int r = s + 1; r <= e; ++r) {
        const float4 v = reinterpret_cast<const float4*>(base + (size_t)r * D_)[d4];
        acc.x += v.x; acc.y += v.y; acc.z += v.z; acc.w += v.w;
    }
    u16x4 hv, lv;
    u16 hh, ll;
    split2(acc.x, hh, ll); hv[0] = hh; lv[0] = ll;
    split2(acc.y, hh, ll); hv[1] = hh; lv[1] = ll;
    split2(acc.z, hh, ll); hv[2] = hh; lv[2] = ll;
    split2(acc.w, hh, ll); hv[3] = hh; lv[3] = ll;
    *(u16x4*)(th + (size_t)bn * D_ + d4 * 4) = hv;
    *(u16x4*)(tl + (size_t)bn * D_ + d4 * 4) = lv;
}

// ---------------------------------------------------------------------------
__global__ __launch_bounds__(192)
void target_max_kernel(const float* __restrict__ se, const int* __restrict__ tspan,
                       float* __restrict__ tmax) {
    const int b = blockIdx.x;
    const int s = tspan[b * 2 + 0];
    const int e = tspan[b * 2 + 1];
    const float* base = se + (size_t)b * S_ * D_;
    const int d4 = threadIdx.x;
    float4 m = make_float4(-FLT_MAX, -FLT_MAX, -FLT_MAX, -FLT_MAX);
    for (int r = s; r < e; ++r) {
        const float4 v = reinterpret_cast<const float4*>(base + (size_t)r * D_)[d4];
        m.x = fmaxf(m.x, v.x); m.y = fmaxf(m.y, v.y);
        m.z = fmaxf(m.z, v.z); m.w = fmaxf(m.w, v.w);
    }
    reinterpret_cast<float4*>(tmax + (size_t)b * D_)[d4] = m;
}

// ---------------------------------------------------------------------------
// adj = clamp(dg+dg1,1) -> bf16 (exact {0,1}); invden[row] = 1/(rowsum+1e-7)
__global__ __launch_bounds__(128)
void adj_kernel(const float* __restrict__ dg, const float* __restrict__ dg1,
                u16* __restrict__ adj, float* __restrict__ invden) {
    const int row = blockIdx.x;
    const int t   = threadIdx.x;
    const size_t idx = (size_t)row * N_ + t;
    float a = dg[idx] + dg1[idx];
    a = (a >= 1.f) ? 1.f : a;
    adj[idx] = bf16_rne(a);
    float w = a;
    #pragma unroll
    for (int off = 32; off; off >>= 1) w += __shfl_down(w, off, 64);
    __shared__ float ssum[2];
    if ((t & 63) == 0) ssum[t >> 6] = w;
    __syncthreads();
    if (t == 0) invden[row] = 1.f / (ssum[0] + ssum[1] + 1e-7f);
}

// ---------------------------------------------------------------------------
// Weights: W[k][n] (768x768) -> WT[n][k] split bf16 hi/lo. blockIdx.z = matrix.
__global__ __launch_bounds__(256)
void wsplit_kernel(const float* __restrict__ W0, const float* __restrict__ W1,
                   const float* __restrict__ W2, const float* __restrict__ W3,
                   u16* __restrict__ wth, u16* __restrict__ wtl) {
    __shared__ float t[64][65];
    const int mi = blockIdx.z;
    const float* W = (mi == 0) ? W0 : (mi == 1) ? W1 : (mi == 2) ? W2 : W3;
    const int k0 = blockIdx.y * 64, n0 = blockIdx.x * 64;
    #pragma unroll 4
    for (int it = 0; it < 16; ++it) {
        const int lin = it * 256 + threadIdx.x;
        const int r = lin >> 6, c = lin & 63;
        t[r][c] = W[(size_t)(k0 + r) * D_ + n0 + c];
    }
    __syncthreads();
    u16* oh = wth + (size_t)mi * D_ * D_;
    u16* ol = wtl + (size_t)mi * D_ * D_;
    #pragma unroll 4
    for (int it = 0; it < 16; ++it) {
        const int lin = it * 256 + threadIdx.x;
        const int r = lin >> 6, c = lin & 63;      // out row n0+r, col k0+c
        u16 h, l; split2(t[c][r], h, l);
        oh[(size_t)(n0 + r) * D_ + k0 + c] = h;
        ol[(size_t)(n0 + r) * D_ + k0 + c] = l;
    }
}

// ---------------------------------------------------------------------------
// Split-bf16 GEMM: C[M=8192,N=768] = (Ah+Al)[M,768] @ (Bh+Bl)^T-stored[768,768]
// (B given as WT[n][k]).  EPI=0: relu -> Oh/Ol = X hi/lo row-major [m][768].
// EPI=1: no relu -> Oh/Ol = hWT hi/lo per-batch [b][768 d][128 n] (b=blockIdx.y).
template<int EPI>
__global__ __launch_bounds__(256)
void gemm_split(const u16* __restrict__ Ah, const u16* __restrict__ Al,
                const u16* __restrict__ Bh, const u16* __restrict__ Bl,
                u16* __restrict__ Oh, u16* __restrict__ Ol) {
    __shared__ u16 sAh[4096], sAl[4096], sBh[4096], sBl[4096];
    const int tid  = threadIdx.x;
    const int lane = tid & 63, w = tid >> 6;
    const int wr = w >> 1, wc = w & 1;
    const int lr = lane & 15, lh = lane >> 4;
    const int bm = blockIdx.y * 128, bn = blockIdx.x * 128;

    const u16* gsrc = (w == 0) ? Ah + (size_t)bm * 768
                    : (w == 1) ? Al + (size_t)bm * 768
                    : (w == 2) ? Bh + (size_t)bn * 768
                               : Bl + (size_t)bn * 768;
    u16* sdst = (w == 0) ? sAh : (w == 1) ? sAl : (w == 2) ? sBh : sBl;

    f32x4 acc[4][4];
    #pragma unroll
    for (int i = 0; i < 4; ++i)
        #pragma unroll
        for (int j = 0; j < 4; ++j)
            acc[i][j] = (f32x4){0.f, 0.f, 0.f, 0.f};

    for (int k0 = 0; k0 < 768; k0 += 32) {
        stage_tile(gsrc + k0, sdst, lane, 768);
        asm volatile("s_waitcnt vmcnt(0)" ::: "memory");
        __syncthreads();
        short8 ah[4], al[4], bh[4], bl[4];
        #pragma unroll
        for (int f = 0; f < 4; ++f) {
            ah[f] = *(const short8*)&sAh[(wr * 64 + f * 16 + lr) * 32 + lh * 8];
            al[f] = *(const short8*)&sAl[(wr * 64 + f * 16 + lr) * 32 + lh * 8];
            bh[f] = *(const short8*)&sBh[(wc * 64 + f * 16 + lr) * 32 + lh * 8];
            bl[f] = *(const short8*)&sBl[(wc * 64 + f * 16 + lr) * 32 + lh * 8];
        }
        #pragma unroll
        for (int mf = 0; mf < 4; ++mf)
            #pragma unroll
            for (int nf = 0; nf < 4; ++nf) {
                acc[mf][nf] = __builtin_amdgcn_mfma_f32_16x16x32_bf16(ah[mf], bh[nf], acc[mf][nf], 0, 0, 0);
                acc[mf][nf] = __builtin_amdgcn_mfma_f32_16x16x32_bf16(ah[mf], bl[nf], acc[mf][nf], 0, 0, 0);
                acc[mf][nf] = __builtin_amdgcn_mfma_f32_16x16x32_bf16(al[mf], bh[nf], acc[mf][nf], 0, 0, 0);
            }
        __syncthreads();
    }

    if (EPI == 0) {
        #pragma unroll
        for (int mf = 0; mf < 4; ++mf) {
            const int m0 = bm + wr * 64 + mf * 16 + lh * 4;
            #pragma unroll
            for (int nf = 0; nf < 4; ++nf) {
                const int col = bn + wc * 64 + nf * 16 + lr;
                #pragma unroll
                for (int r = 0; r < 4; ++r) {
                    const float v = fmaxf(acc[mf][nf][r], 0.f);
                    u16 h, l; split2(v, h, l);
                    const size_t gi = (size_t)(m0 + r) * 768 + col;
                    Oh[gi] = h; Ol[gi] = l;
                }
            }
        }
    } else {
        const int b = blockIdx.y;   // BM == N_ == 128
        #pragma unroll
        for (int mf = 0; mf < 4; ++mf) {
            const int n0 = wr * 64 + mf * 16 + lh * 4;
            #pragma unroll
            for (int nf = 0; nf < 4; ++nf) {
                const int col = bn + wc * 64 + nf * 16 + lr;
                u16x4 hv, lv;
                #pragma unroll
                for (int r = 0; r < 4; ++r) {
                    u16 h, l; split2(acc[mf][nf][r], h, l);
                    hv[r] = h; lv[r] = l;
                }
                const size_t o = (size_t)b * (D_ * N_) + (size_t)col * N_ + n0;
                *(u16x4*)&Oh[o] = hv;
                *(u16x4*)&Ol[o] = lv;
            }
        }
    }
}

// ---------------------------------------------------------------------------
// Per-batch: X = relu( (adj[b] @ hW[b]) * invden + bias ) + X_old
// A = adj bf16 [b][128 n][128 m] (exact), B = hWT hi/lo [b][768 d][128 m].
__global__ __launch_bounds__(256)
void adj_gemm_mfma(const u16* __restrict__ ADJ, const u16* __restrict__ Bh,
                   const u16* __restrict__ Bl, const float* __restrict__ invden,
                   const float* __restrict__ bias,
                   u16* __restrict__ Xh, u16* __restrict__ Xl) {
    __shared__ u16 sA[4096], sBh[4096], sBl[4096];
    const int tid  = threadIdx.x;
    const int lane = tid & 63, w = tid >> 6;
    const int wr = w >> 1, wc = w & 1;
    const int lr = lane & 15, lh = lane >> 4;
    const int b  = blockIdx.y;
    const int bn = blockIdx.x * 128;

    const u16* gsrc = (w == 0) ? ADJ + (size_t)b * (N_ * N_)
                    : (w == 1) ? Bh + (size_t)b * (D_ * N_) + (size_t)bn * N_
                               : Bl + (size_t)b * (D_ * N_) + (size_t)bn * N_;
    u16* sdst = (w == 0) ? sA : (w == 1) ? sBh : sBl;

    f32x4 acc[4][4];
    #pragma unroll
    for (int i = 0; i < 4; ++i)
        #pragma unroll
        for (int j = 0; j < 4; ++j)
            acc[i][j] = (f32x4){0.f, 0.f, 0.f, 0.f};

    for (int k0 = 0; k0 < 128; k0 += 32) {
        if (w < 3) stage_tile(gsrc + k0, sdst, lane, 128);
        asm volatile("s_waitcnt vmcnt(0)" ::: "memory");
        __syncthreads();
        short8 aa[4], bh[4], bl[4];
        #pragma unroll
        for (int f = 0; f < 4; ++f) {
            aa[f] = *(const short8*)&sA [(wr * 64 + f * 16 + lr) * 32 + lh * 8];
            bh[f] = *(const short8*)&sBh[(wc * 64 + f * 16 + lr) * 32 + lh * 8];
            bl[f] = *(const short8*)&sBl[(wc * 64 + f * 16 + lr) * 32 + lh * 8];
        }
        #pragma unroll
        for (int mf = 0; mf < 4; ++mf)
            #pragma unroll
            for (int nf = 0; nf < 4; ++nf) {
                acc[mf][nf] = __builtin_amdgcn_mfma_f32_16x16x32_bf16(aa[mf], bh[nf], acc[mf][nf], 0, 0, 0);
                acc[mf][nf] = __builtin_amdgcn_mfma_f32_16x16x32_bf16(aa[mf], bl[nf], acc[mf][nf], 0, 0, 0);
            }
        __syncthreads();
    }

    #pragma unroll
    for (int mf = 0; mf < 4; ++mf) {
        const int n0 = wr * 64 + mf * 16 + lh * 4;
        #pragma unroll
        for (int r = 0; r < 4; ++r) {
            const int nn = n0 + r;
            const float inv = invden[b * N_ + nn];
            #pragma unroll
            for (int nf = 0; nf < 4; ++nf) {
                const int col = bn + wc * 64 + nf * 16 + lr;
                const float v = fmaxf(acc[mf][nf][r] * inv + bias[col], 0.f);
                const size_t gi = (size_t)(b * N_ + nn) * D_ + col;
                const float old = bf2f(Xh[gi]) + bf2f(Xl[gi]);
                u16 h, l; split2(v + old, h, l);
                Xh[gi] = h; Xl[gi] = l;
            }
        }
    }
}

// ---------------------------------------------------------------------------
__global__ __launch_bounds__(192)
void gcn_target_kernel(const u16* __restrict__ Xh, const u16* __restrict__ Xl,
                       const int* __restrict__ gspan, float* __restrict__ gt) {
    const int b = blockIdx.x;
    const int s = gspan[b * 2 + 0];
    const int e = gspan[b * 2 + 1];
    const int d4 = threadIdx.x;
    float4 acc = make_float4(0.f, 0.f, 0.f, 0.f);
    for (int n = s; n < e; ++n) {
        const size_t base = (size_t)(b * N_ + n) * D_ + d4 * 4;
        const u16x4 h = *(const u16x4*)(Xh + base);
        const u16x4 l = *(const u16x4*)(Xl + base);
        acc.x += bf2f(h[0]) + bf2f(l[0]);
        acc.y += bf2f(h[1]) + bf2f(l[1]);
        acc.z += bf2f(h[2]) + bf2f(l[2]);
        acc.w += bf2f(h[3]) + bf2f(l[3]);
    }
    reinterpret_cast<float4*>(gt + (size_t)b * D_)[d4] = acc;
}

// ---------------------------------------------------------------------------
__global__ __launch_bounds__(256)
void head_kernel(const float* __restrict__ tmax, const float* __restrict__ gt,
                 const float* __restrict__ fcW, const float* __restrict__ fcb,
                 float* __restrict__ out) {
    const int b = blockIdx.x;
    const int t = threadIdx.x;
    float p0 = 0.f, p1 = 0.f, p2 = 0.f;
    for (int i = t; i < 2 * D_; i += 256) {
        const float v = (i < D_) ? tmax[(size_t)b * D_ + i] : gt[(size_t)b * D_ + i - D_];
        p0 += v * fcW[i * 3 + 0];
        p1 += v * fcW[i * 3 + 1];
        p2 += v * fcW[i * 3 + 2];
    }
    #pragma unroll
    for (int off = 32; off; off >>= 1) {
        p0 += __shfl_down(p0, off, 64);
        p1 += __shfl_down(p1, off, 64);
        p2 += __shfl_down(p2, off, 64);
    }
    __shared__ float red[4][3];
    const int wv = t >> 6;
    if ((t & 63) == 0) { red[wv][0] = p0; red[wv][1] = p1; red[wv][2] = p2; }
    __syncthreads();
    if (t == 0) {
        #pragma unroll
        for (int o = 0; o < 3; ++o) {
            const float s = red[0][o] + red[1][o] + red[2][o] + red[3][o] + fcb[o];
            out[b * 3 + o] = tanhf(s);
        }
    }
}

// ---------------------------------------------------------------------------
extern "C" void kernel_launch(void* const* d_in, const int* in_sizes, int n_in,
                              void* d_out, int out_size, void* d_ws, size_t ws_size,
                              hipStream_t stream) {
    const float* se   = (const float*)d_in[0];
    const float* dg   = (const float*)d_in[1];
    const float* dg1  = (const float*)d_in[2];
    const float* Wp   = (const float*)d_in[3];
    const float* Wg[3] = {(const float*)d_in[4], (const float*)d_in[6], (const float*)d_in[8]};
    const float* bg[3] = {(const float*)d_in[5], (const float*)d_in[7], (const float*)d_in[9]};
    const float* fcW  = (const float*)d_in[10];
    const float* fcb  = (const float*)d_in[11];
    const int*   tspan  = (const int*)d_in[12];
    const int*   nspans = (const int*)d_in[13];
    const int*   gspan  = (const int*)d_in[14];
    float* out = (float*)d_out;

    // workspace layout (u16 units unless noted)
    u16* us    = (u16*)d_ws;
    u16* Xh    = us;                       // 8192*768
    u16* Xl    = Xh   + 6291456;
    u16* hWTh  = Xl   + 6291456;           // aliases TMPSh (dead after layer-0 gemm)
    u16* hWTl  = hWTh + 6291456;           // aliases TMPSl
    u16* WTh   = hWTl + 6291456;           // 4*768*768
    u16* WTl   = WTh  + 2359296;
    u16* ADJ   = WTl  + 2359296;           // 64*128*128
    float* INV = (float*)(ADJ + 1048576);  // 8192
    float* TMX = INV + 8192;               // 64*768
    float* GT  = TMX + 49152;              // 64*768

    // Stage A: ragged prep
    span_split_kernel<<<B_ * N_, 192, 0, stream>>>(se, nspans, hWTh, hWTl);
    target_max_kernel<<<B_, 192, 0, stream>>>(se, tspan, TMX);
    adj_kernel<<<B_ * N_, 128, 0, stream>>>(dg, dg1, ADJ, INV);
    wsplit_kernel<<<dim3(12, 12, 4), 256, 0, stream>>>(Wp, Wg[0], Wg[1], Wg[2], WTh, WTl);

    dim3 ggrid(D_ / 128, (B_ * N_) / 128);   // (6, 64)

    // Stage B: X = relu(tmps @ W_proj)
    gemm_split<0><<<ggrid, 256, 0, stream>>>(hWTh, hWTl, WTh, WTl, Xh, Xl);

    // Stage C: 3 GCN layers
    for (int l = 0; l < 3; ++l) {
        const size_t wo = (size_t)(l + 1) * D_ * D_;
        gemm_split<1><<<ggrid, 256, 0, stream>>>(Xh, Xl, WTh + wo, WTl + wo, hWTh, hWTl);
        adj_gemm_mfma<<<ggrid, 256, 0, stream>>>(ADJ, hWTh, hWTl, INV, bg[l], Xh, Xl);
    }

    // Stage D: ragged node-span sum + head
    gcn_target_kernel<<<B_, 192, 0, stream>>>(Xh, Xl, gspan, GT);
    head_kernel<<<B_, 256, 0, stream>>>(TMX, GT, fcW, fcb, out);
}

// Round 3
// 212.536 us; speedup vs baseline: 3.2589x; 1.6325x over previous
//
#include <hip/hip_runtime.h>
#include <float.h>
#include <math.h>

typedef __attribute__((ext_vector_type(8))) short short8;
typedef __attribute__((ext_vector_type(4))) float f32x4;
typedef __attribute__((ext_vector_type(4))) unsigned short u16x4;
typedef unsigned short u16;
typedef unsigned int u32;

constexpr int B_ = 64, S_ = 512, N_ = 128, D_ = 768;

// ---------------------------------------------------------------------------
__device__ inline u16 bf16_rne(float x) {
    u32 u = __builtin_bit_cast(u32, x);
    u += 0x7FFFu + ((u >> 16) & 1u);
    return (u16)(u >> 16);
}
__device__ inline float bf2f(u16 h) {
    u32 u = ((u32)h) << 16;
    return __builtin_bit_cast(float, u);
}
__device__ inline void split2(float x, u16& h, u16& l) {
    h = bf16_rne(x);
    l = bf16_rne(x - bf2f(h));
}

__device__ inline void gload_lds16(const u16* g, u16* s) {
    __builtin_amdgcn_global_load_lds(
        (const __attribute__((address_space(1))) u32*)g,
        (__attribute__((address_space(3))) u32*)s, 16, 0, 0);
}

// stage a 128-row x 32-elem bf16 tile (64B rows) into linear LDS. 8 instrs/wave.
__device__ inline void stage_tile(const u16* g, u16* s, int lane, int rowStride) {
    const u16* gb = g + (size_t)(lane >> 2) * rowStride + (size_t)(lane & 3) * 8;
    #pragma unroll
    for (int i = 0; i < 8; ++i)
        gload_lds16(gb + (size_t)(i * 16) * rowStride, s + i * 512);
}

// ---------------------------------------------------------------------------
__global__ __launch_bounds__(192)
void span_split_kernel(const float* __restrict__ se, const int* __restrict__ spans,
                       u16* __restrict__ th, u16* __restrict__ tl) {
    const int bn = blockIdx.x;
    const int b  = bn >> 7;
    const int s  = spans[bn * 2 + 0];
    const int e  = spans[bn * 2 + 1];
    const float* base = se + (size_t)b * S_ * D_;
    const int d4 = threadIdx.x;
    float4 acc = make_float4(0.f, 0.f, 0.f, 0.f);
    for (int r = s + 1; r <= e; ++r) {
        const float4 v = reinterpret_cast<const float4*>(base + (size_t)r * D_)[d4];
        acc.x += v.x; acc.y += v.y; acc.z += v.z; acc.w += v.w;
    }
    u16x4 hv, lv;
    u16 hh, ll;
    split2(acc.x, hh, ll); hv[0] = hh; lv[0] = ll;
    split2(acc.y, hh, ll); hv[1] = hh; lv[1] = ll;
    split2(acc.z, hh, ll); hv[2] = hh; lv[2] = ll;
    split2(acc.w, hh, ll); hv[3] = hh; lv[3] = ll;
    *(u16x4*)(th + (size_t)bn * D_ + d4 * 4) = hv;
    *(u16x4*)(tl + (size_t)bn * D_ + d4 * 4) = lv;
}

// ---------------------------------------------------------------------------
__global__ __launch_bounds__(192)
void target_max_kernel(const float* __restrict__ se, const int* __restrict__ tspan,
                       float* __restrict__ tmax) {
    const int b = blockIdx.x;
    const int s = tspan[b * 2 + 0];
    const int e = tspan[b * 2 + 1];
    const float* base = se + (size_t)b * S_ * D_;
    const int d4 = threadIdx.x;
    float4 m = make_float4(-FLT_MAX, -FLT_MAX, -FLT_MAX, -FLT_MAX);
    for (int r = s; r < e; ++r) {
        const float4 v = reinterpret_cast<const float4*>(base + (size_t)r * D_)[d4];
        m.x = fmaxf(m.x, v.x); m.y = fmaxf(m.y, v.y);
        m.z = fmaxf(m.z, v.z); m.w = fmaxf(m.w, v.w);
    }
    reinterpret_cast<float4*>(tmax + (size_t)b * D_)[d4] = m;
}

// ---------------------------------------------------------------------------
// adj = clamp(dg+dg1,1) -> bf16 (exact {0,1}) [b][n][k]; invden = 1/(rowsum+1e-7)
__global__ __launch_bounds__(128)
void adj_kernel(const float* __restrict__ dg, const float* __restrict__ dg1,
                u16* __restrict__ adj, float* __restrict__ invden) {
    const int row = blockIdx.x;
    const int t   = threadIdx.x;
    const size_t idx = (size_t)row * N_ + t;
    float a = dg[idx] + dg1[idx];
    a = (a >= 1.f) ? 1.f : a;
    adj[idx] = bf16_rne(a);
    float w = a;
    #pragma unroll
    for (int off = 32; off; off >>= 1) w += __shfl_down(w, off, 64);
    __shared__ float ssum[2];
    if ((t & 63) == 0) ssum[t >> 6] = w;
    __syncthreads();
    if (t == 0) invden[row] = 1.f / (ssum[0] + ssum[1] + 1e-7f);
}

// ---------------------------------------------------------------------------
// Weights: W[k][n] (768x768) -> WT[n][k] split bf16 hi/lo. blockIdx.z = matrix.
__global__ __launch_bounds__(256)
void wsplit_kernel(const float* __restrict__ W0, const float* __restrict__ W1,
                   const float* __restrict__ W2, const float* __restrict__ W3,
                   u16* __restrict__ wth, u16* __restrict__ wtl) {
    __shared__ float t[64][65];
    const int mi = blockIdx.z;
    const float* W = (mi == 0) ? W0 : (mi == 1) ? W1 : (mi == 2) ? W2 : W3;
    const int k0 = blockIdx.y * 64, n0 = blockIdx.x * 64;
    #pragma unroll 4
    for (int it = 0; it < 16; ++it) {
        const int lin = it * 256 + threadIdx.x;
        const int r = lin >> 6, c = lin & 63;
        t[r][c] = W[(size_t)(k0 + r) * D_ + n0 + c];
    }
    __syncthreads();
    u16* oh = wth + (size_t)mi * D_ * D_;
    u16* ol = wtl + (size_t)mi * D_ * D_;
    #pragma unroll 4
    for (int it = 0; it < 16; ++it) {
        const int lin = it * 256 + threadIdx.x;
        const int r = lin >> 6, c = lin & 63;
        u16 h, l; split2(t[c][r], h, l);
        oh[(size_t)(n0 + r) * D_ + k0 + c] = h;
        ol[(size_t)(n0 + r) * D_ + k0 + c] = l;
    }
}

// ---------------------------------------------------------------------------
// Fused split-bf16 GEMM (+ optional adjacency GEMM phase).
// Phase 1: H = (Ah+Al)[M,768] @ (Bh+Bl)(stored as WT[n][k]).  3 MFMA products.
// MODE 0: store relu(H) split hi/lo row-major (first projection).
// MODE 1: phase 2 in-LDS: out = relu( (adj[b] @ H) * invden + bias ) + X_in,
//         where block (bm=b*128, bn) holds the FULL K=128 extent of H for b.
//         A-source (Ah/Al) doubles as the residual X_in. Output ping-pongs.
template<int MODE>
__global__ __launch_bounds__(256)
void gemm_fused(const u16* __restrict__ Ah, const u16* __restrict__ Al,
                const u16* __restrict__ Bh, const u16* __restrict__ Bl,
                const u16* __restrict__ ADJ, const float* __restrict__ invden,
                const float* __restrict__ bias,
                u16* __restrict__ Oh, u16* __restrict__ Ol) {
    __shared__ u16 lds[2][16384];   // each buf: 4 tiles x (128 rows x 32 k)
    const int tid  = threadIdx.x;
    const int lane = tid & 63, w = tid >> 6;
    const int wr = w >> 1, wc = w & 1;
    const int lr = lane & 15, lh = lane >> 4;

    int bid = blockIdx.x;
    bid = (bid & 7) * 48 + (bid >> 3);      // XCD swizzle, 384 % 8 == 0 (bijective)
    const int bnb = bid % 6, bmb = bid / 6;
    const int bm = bmb * 128, bn = bnb * 128;

    const u16* gsrc = (w == 0) ? Ah + (size_t)bm * 768
                    : (w == 1) ? Al + (size_t)bm * 768
                    : (w == 2) ? Bh + (size_t)bn * 768
                               : Bl + (size_t)bn * 768;

    f32x4 acc[4][4];
    #pragma unroll
    for (int i = 0; i < 4; ++i)
        #pragma unroll
        for (int j = 0; j < 4; ++j)
            acc[i][j] = (f32x4){0.f, 0.f, 0.f, 0.f};

    // prologue: stage tile 0 into buf0
    stage_tile(gsrc, &lds[0][w * 4096], lane, 768);

    for (int t = 0; t < 24; ++t) {
        if (t < 23) {
            stage_tile(gsrc + (t + 1) * 32, &lds[(t + 1) & 1][w * 4096], lane, 768);
            asm volatile("s_waitcnt vmcnt(8)" ::: "memory");
        } else if (MODE == 1) {
            // stage adj[b] (128x128 bf16, [n][k]) into buf0, XOR-swizzled via
            // pre-swizzled GLOBAL source (LDS dest must stay linear).
            const u16* adjb = ADJ + (size_t)bmb * (N_ * N_);
            #pragma unroll
            for (int i = 0; i < 8; ++i) {
                const int n = w * 32 + i * 4 + lh;
                gload_lds16(adjb + (size_t)n * 128 + ((lr ^ (n & 7)) << 3),
                            &lds[0][w * 4096 + i * 512]);
            }
            asm volatile("s_waitcnt vmcnt(8)" ::: "memory");
        } else {
            asm volatile("s_waitcnt vmcnt(0)" ::: "memory");
        }
        __builtin_amdgcn_s_barrier();
        __builtin_amdgcn_sched_barrier(0);

        const u16* L = lds[t & 1];
        short8 ah[4], al[4], bh4[4], bl4[4];
        #pragma unroll
        for (int f = 0; f < 4; ++f) {
            const int ra = (wr * 64 + f * 16 + lr) * 32 + lh * 8;
            const int rb = (wc * 64 + f * 16 + lr) * 32 + lh * 8;
            ah[f]  = *(const short8*)&L[ra];
            al[f]  = *(const short8*)&L[4096 + ra];
            bh4[f] = *(const short8*)&L[8192 + rb];
            bl4[f] = *(const short8*)&L[12288 + rb];
        }
        #pragma unroll
        for (int mf = 0; mf < 4; ++mf)
            #pragma unroll
            for (int nf = 0; nf < 4; ++nf) {
                acc[mf][nf] = __builtin_amdgcn_mfma_f32_16x16x32_bf16(ah[mf], bh4[nf], acc[mf][nf], 0, 0, 0);
                acc[mf][nf] = __builtin_amdgcn_mfma_f32_16x16x32_bf16(ah[mf], bl4[nf], acc[mf][nf], 0, 0, 0);
                acc[mf][nf] = __builtin_amdgcn_mfma_f32_16x16x32_bf16(al[mf], bh4[nf], acc[mf][nf], 0, 0, 0);
            }
        asm volatile("s_waitcnt lgkmcnt(0)" ::: "memory");
        __builtin_amdgcn_s_barrier();
    }

    if (MODE == 0) {
        #pragma unroll
        for (int mf = 0; mf < 4; ++mf)
            #pragma unroll
            for (int r = 0; r < 4; ++r) {
                const int row = bm + wr * 64 + mf * 16 + lh * 4 + r;
                #pragma unroll
                for (int nf = 0; nf < 4; ++nf) {
                    const int c = bn + wc * 64 + nf * 16 + lr;
                    const float v = fmaxf(acc[mf][nf][r], 0.f);
                    u16 h, l; split2(v, h, l);
                    const size_t gi = (size_t)row * 768 + c;
                    Oh[gi] = h; Ol[gi] = l;
                }
            }
        return;
    }

    // ---------------- MODE 1: phase 2 (adjacency GEMM in-LDS) ----------------
    asm volatile("s_waitcnt vmcnt(0)" ::: "memory");   // adj staged
    __builtin_amdgcn_s_barrier();
    __builtin_amdgcn_sched_barrier(0);

    u16* hwT = lds[1];             // H^T tile [c 128][k 128], XOR-swizzled slots
    const u16* adjL = lds[0];      // adj tile [n 128][k 128], XOR-swizzled slots

    // write HI halves of H^T; keep LO in registers
    u16x4 lv[4][4];
    #pragma unroll
    for (int mf = 0; mf < 4; ++mf) {
        const int node0 = wr * 64 + mf * 16 + lh * 4;
        #pragma unroll
        for (int nf = 0; nf < 4; ++nf) {
            const int c = wc * 64 + nf * 16 + lr;
            u16x4 hv;
            #pragma unroll
            for (int r = 0; r < 4; ++r) {
                u16 h, l; split2(acc[mf][nf][r], h, l);
                hv[r] = h; lv[mf][nf][r] = l;
            }
            *(u16x4*)&hwT[c * 128 + (((node0 >> 3) ^ (c & 7)) << 3) + (node0 & 7)] = hv;
        }
    }
    asm volatile("s_waitcnt lgkmcnt(0)" ::: "memory");
    __builtin_amdgcn_s_barrier();
    __builtin_amdgcn_sched_barrier(0);

    f32x4 acc2[4][4];
    #pragma unroll
    for (int i = 0; i < 4; ++i)
        #pragma unroll
        for (int j = 0; j < 4; ++j)
            acc2[i][j] = (f32x4){0.f, 0.f, 0.f, 0.f};

    #pragma unroll
    for (int pass = 0; pass < 2; ++pass) {
        if (pass == 1) {
            // overwrite with LO halves
            #pragma unroll
            for (int mf = 0; mf < 4; ++mf) {
                const int node0 = wr * 64 + mf * 16 + lh * 4;
                #pragma unroll
                for (int nf = 0; nf < 4; ++nf) {
                    const int c = wc * 64 + nf * 16 + lr;
                    *(u16x4*)&hwT[c * 128 + (((node0 >> 3) ^ (c & 7)) << 3) + (node0 & 7)] = lv[mf][nf];
                }
            }
            asm volatile("s_waitcnt lgkmcnt(0)" ::: "memory");
            __builtin_amdgcn_s_barrier();
            __builtin_amdgcn_sched_barrier(0);
        }
        #pragma unroll
        for (int ks = 0; ks < 4; ++ks) {
            short8 af[4], bf[4];
            #pragma unroll
            for (int f = 0; f < 4; ++f) {
                const int node = wr * 64 + f * 16 + lr;
                af[f] = *(const short8*)&adjL[node * 128 + ((((ks << 2) | lh) ^ (node & 7)) << 3)];
                const int c = wc * 64 + f * 16 + lr;
                bf[f] = *(const short8*)&hwT[c * 128 + ((((ks << 2) | lh) ^ (c & 7)) << 3)];
            }
            #pragma unroll
            for (int mf = 0; mf < 4; ++mf)
                #pragma unroll
                for (int nf = 0; nf < 4; ++nf)
                    acc2[mf][nf] = __builtin_amdgcn_mfma_f32_16x16x32_bf16(af[mf], bf[nf], acc2[mf][nf], 0, 0, 0);
        }
        if (pass == 0) {
            asm volatile("s_waitcnt lgkmcnt(0)" ::: "memory");
            __builtin_amdgcn_s_barrier();
            __builtin_amdgcn_sched_barrier(0);
        }
    }

    // epilogue: out = relu(acc2*inv + bias) + X_in; split; store
    const int b = bmb;
    #pragma unroll
    for (int mf = 0; mf < 4; ++mf)
        #pragma unroll
        for (int r = 0; r < 4; ++r) {
            const int node = wr * 64 + mf * 16 + lh * 4 + r;
            const float inv = invden[b * N_ + node];
            const size_t rowbase = (size_t)(b * N_ + node) * 768 + bn;
            #pragma unroll
            for (int nf = 0; nf < 4; ++nf) {
                const int c = wc * 64 + nf * 16 + lr;
                float v = fmaxf(acc2[mf][nf][r] * inv + bias[bn + c], 0.f);
                const size_t gi = rowbase + c;
                v += bf2f(Ah[gi]) + bf2f(Al[gi]);   // residual = A-source
                u16 h, l; split2(v, h, l);
                Oh[gi] = h; Ol[gi] = l;
            }
        }
}

// ---------------------------------------------------------------------------
__global__ __launch_bounds__(192)
void gcn_target_kernel(const u16* __restrict__ Xh, const u16* __restrict__ Xl,
                       const int* __restrict__ gspan, float* __restrict__ gt) {
    const int b = blockIdx.x;
    const int s = gspan[b * 2 + 0];
    const int e = gspan[b * 2 + 1];
    const int d4 = threadIdx.x;
    float4 acc = make_float4(0.f, 0.f, 0.f, 0.f);
    for (int n = s; n < e; ++n) {
        const size_t base = (size_t)(b * N_ + n) * D_ + d4 * 4;
        const u16x4 h = *(const u16x4*)(Xh + base);
        const u16x4 l = *(const u16x4*)(Xl + base);
        acc.x += bf2f(h[0]) + bf2f(l[0]);
        acc.y += bf2f(h[1]) + bf2f(l[1]);
        acc.z += bf2f(h[2]) + bf2f(l[2]);
        acc.w += bf2f(h[3]) + bf2f(l[3]);
    }
    reinterpret_cast<float4*>(gt + (size_t)b * D_)[d4] = acc;
}

// ---------------------------------------------------------------------------
__global__ __launch_bounds__(256)
void head_kernel(const float* __restrict__ tmax, const float* __restrict__ gt,
                 const float* __restrict__ fcW, const float* __restrict__ fcb,
                 float* __restrict__ out) {
    const int b = blockIdx.x;
    const int t = threadIdx.x;
    float p0 = 0.f, p1 = 0.f, p2 = 0.f;
    for (int i = t; i < 2 * D_; i += 256) {
        const float v = (i < D_) ? tmax[(size_t)b * D_ + i] : gt[(size_t)b * D_ + i - D_];
        p0 += v * fcW[i * 3 + 0];
        p1 += v * fcW[i * 3 + 1];
        p2 += v * fcW[i * 3 + 2];
    }
    #pragma unroll
    for (int off = 32; off; off >>= 1) {
        p0 += __shfl_down(p0, off, 64);
        p1 += __shfl_down(p1, off, 64);
        p2 += __shfl_down(p2, off, 64);
    }
    __shared__ float red[4][3];
    const int wv = t >> 6;
    if ((t & 63) == 0) { red[wv][0] = p0; red[wv][1] = p1; red[wv][2] = p2; }
    __syncthreads();
    if (t == 0) {
        #pragma unroll
        for (int o = 0; o < 3; ++o) {
            const float s = red[0][o] + red[1][o] + red[2][o] + red[3][o] + fcb[o];
            out[b * 3 + o] = tanhf(s);
        }
    }
}

// ---------------------------------------------------------------------------
extern "C" void kernel_launch(void* const* d_in, const int* in_sizes, int n_in,
                              void* d_out, int out_size, void* d_ws, size_t ws_size,
                              hipStream_t stream) {
    const float* se   = (const float*)d_in[0];
    const float* dg   = (const float*)d_in[1];
    const float* dg1  = (const float*)d_in[2];
    const float* Wp   = (const float*)d_in[3];
    const float* Wg[3] = {(const float*)d_in[4], (const float*)d_in[6], (const float*)d_in[8]};
    const float* bg[3] = {(const float*)d_in[5], (const float*)d_in[7], (const float*)d_in[9]};
    const float* fcW  = (const float*)d_in[10];
    const float* fcb  = (const float*)d_in[11];
    const int*   tspan  = (const int*)d_in[12];
    const int*   nspans = (const int*)d_in[13];
    const int*   gspan  = (const int*)d_in[14];
    float* out = (float*)d_out;

    // workspace layout (u16 units unless noted)
    u16* us   = (u16*)d_ws;
    u16* X0h  = us;                        // 8192*768 each
    u16* X0l  = X0h + 6291456;
    u16* X1h  = X0l + 6291456;
    u16* X1l  = X1h + 6291456;
    u16* TH   = X1l + 6291456;             // tmps hi/lo
    u16* TL   = TH  + 6291456;
    u16* WTh  = TL  + 6291456;             // 4*768*768
    u16* WTl  = WTh + 2359296;
    u16* ADJ  = WTl + 2359296;             // 64*128*128
    float* INV = (float*)(ADJ + 1048576);  // 8192
    float* TMX = INV + 8192;               // 64*768
    float* GT  = TMX + 49152;              // 64*768

    // Stage A: ragged prep
    span_split_kernel<<<B_ * N_, 192, 0, stream>>>(se, nspans, TH, TL);
    target_max_kernel<<<B_, 192, 0, stream>>>(se, tspan, TMX);
    adj_kernel<<<B_ * N_, 128, 0, stream>>>(dg, dg1, ADJ, INV);
    wsplit_kernel<<<dim3(12, 12, 4), 256, 0, stream>>>(Wp, Wg[0], Wg[1], Wg[2], WTh, WTl);

    // Stage B: X0 = relu(tmps @ W_proj)
    gemm_fused<0><<<384, 256, 0, stream>>>(TH, TL, WTh, WTl,
                                           nullptr, nullptr, nullptr, X0h, X0l);

    // Stage C: 3 fused GCN layers (ping-pong X0 <-> X1)
    const u16* inh[3] = {X0h, X1h, X0h};
    const u16* inl[3] = {X0l, X1l, X0l};
    u16* outh[3] = {X1h, X0h, X1h};
    u16* outl[3] = {X1l, X0l, X1l};
    for (int l = 0; l < 3; ++l) {
        const size_t wo = (size_t)(l + 1) * D_ * D_;
        gemm_fused<1><<<384, 256, 0, stream>>>(inh[l], inl[l], WTh + wo, WTl + wo,
                                               ADJ, INV, bg[l], outh[l], outl[l]);
    }

    // Stage D: ragged node-span sum + head (final X lives in X1)
    gcn_target_kernel<<<B_, 192, 0, stream>>>(X1h, X1l, gspan, GT);
    head_kernel<<<B_, 256, 0, stream>>>(TMX, GT, fcW, fcb, out);
}

// Round 4
// 200.270 us; speedup vs baseline: 3.4585x; 1.0612x over previous
//
#include <hip/hip_runtime.h>
#include <float.h>
#include <math.h>

typedef __attribute__((ext_vector_type(8))) short short8;
typedef __attribute__((ext_vector_type(4))) float f32x4;
typedef __attribute__((ext_vector_type(4))) unsigned short u16x4;
typedef unsigned short u16;
typedef unsigned int u32;

constexpr int B_ = 64, S_ = 512, N_ = 128, D_ = 768;

// ---------------------------------------------------------------------------
__device__ inline u16 bf16_rne(float x) {
    u32 u = __builtin_bit_cast(u32, x);
    u += 0x7FFFu + ((u >> 16) & 1u);
    return (u16)(u >> 16);
}
__device__ inline float bf2f(u16 h) {
    u32 u = ((u32)h) << 16;
    return __builtin_bit_cast(float, u);
}
__device__ inline void split2(float x, u16& h, u16& l) {
    h = bf16_rne(x);
    l = bf16_rne(x - bf2f(h));
}

__device__ inline void gload_lds16(const u16* g, u16* s) {
    __builtin_amdgcn_global_load_lds(
        (const __attribute__((address_space(1))) u32*)g,
        (__attribute__((address_space(3))) u32*)s, 16, 0, 0);
}

// ---------------------------------------------------------------------------
__global__ __launch_bounds__(192)
void span_split_kernel(const float* __restrict__ se, const int* __restrict__ spans,
                       u16* __restrict__ th, u16* __restrict__ tl) {
    const int bn = blockIdx.x;
    const int b  = bn >> 7;
    const int s  = spans[bn * 2 + 0];
    const int e  = spans[bn * 2 + 1];
    const float* base = se + (size_t)b * S_ * D_;
    const int d4 = threadIdx.x;
    float4 acc = make_float4(0.f, 0.f, 0.f, 0.f);
    for (int r = s + 1; r <= e; ++r) {
        const float4 v = reinterpret_cast<const float4*>(base + (size_t)r * D_)[d4];
        acc.x += v.x; acc.y += v.y; acc.z += v.z; acc.w += v.w;
    }
    u16x4 hv, lv;
    u16 hh, ll;
    split2(acc.x, hh, ll); hv[0] = hh; lv[0] = ll;
    split2(acc.y, hh, ll); hv[1] = hh; lv[1] = ll;
    split2(acc.z, hh, ll); hv[2] = hh; lv[2] = ll;
    split2(acc.w, hh, ll); hv[3] = hh; lv[3] = ll;
    *(u16x4*)(th + (size_t)bn * D_ + d4 * 4) = hv;
    *(u16x4*)(tl + (size_t)bn * D_ + d4 * 4) = lv;
}

// ---------------------------------------------------------------------------
__global__ __launch_bounds__(192)
void target_max_kernel(const float* __restrict__ se, const int* __restrict__ tspan,
                       float* __restrict__ tmax) {
    const int b = blockIdx.x;
    const int s = tspan[b * 2 + 0];
    const int e = tspan[b * 2 + 1];
    const float* base = se + (size_t)b * S_ * D_;
    const int d4 = threadIdx.x;
    float4 m = make_float4(-FLT_MAX, -FLT_MAX, -FLT_MAX, -FLT_MAX);
    for (int r = s; r < e; ++r) {
        const float4 v = reinterpret_cast<const float4*>(base + (size_t)r * D_)[d4];
        m.x = fmaxf(m.x, v.x); m.y = fmaxf(m.y, v.y);
        m.z = fmaxf(m.z, v.z); m.w = fmaxf(m.w, v.w);
    }
    reinterpret_cast<float4*>(tmax + (size_t)b * D_)[d4] = m;
}

// ---------------------------------------------------------------------------
// adj = clamp(dg+dg1,1) -> bf16 (exact {0,1}) [b][n][k]; invden = 1/(rowsum+1e-7)
__global__ __launch_bounds__(128)
void adj_kernel(const float* __restrict__ dg, const float* __restrict__ dg1,
                u16* __restrict__ adj, float* __restrict__ invden) {
    const int row = blockIdx.x;
    const int t   = threadIdx.x;
    const size_t idx = (size_t)row * N_ + t;
    float a = dg[idx] + dg1[idx];
    a = (a >= 1.f) ? 1.f : a;
    adj[idx] = bf16_rne(a);
    float w = a;
    #pragma unroll
    for (int off = 32; off; off >>= 1) w += __shfl_down(w, off, 64);
    __shared__ float ssum[2];
    if ((t & 63) == 0) ssum[t >> 6] = w;
    __syncthreads();
    if (t == 0) invden[row] = 1.f / (ssum[0] + ssum[1] + 1e-7f);
}

// ---------------------------------------------------------------------------
// Weights: W[k][n] (768x768) -> WT[n][k] split bf16 hi/lo. blockIdx.z = matrix.
__global__ __launch_bounds__(256)
void wsplit_kernel(const float* __restrict__ W0, const float* __restrict__ W1,
                   const float* __restrict__ W2, const float* __restrict__ W3,
                   u16* __restrict__ wth, u16* __restrict__ wtl) {
    __shared__ float t[64][65];
    const int mi = blockIdx.z;
    const float* W = (mi == 0) ? W0 : (mi == 1) ? W1 : (mi == 2) ? W2 : W3;
    const int k0 = blockIdx.y * 64, n0 = blockIdx.x * 64;
    #pragma unroll 4
    for (int it = 0; it < 16; ++it) {
        const int lin = it * 256 + threadIdx.x;
        const int r = lin >> 6, c = lin & 63;
        t[r][c] = W[(size_t)(k0 + r) * D_ + n0 + c];
    }
    __syncthreads();
    u16* oh = wth + (size_t)mi * D_ * D_;
    u16* ol = wtl + (size_t)mi * D_ * D_;
    #pragma unroll 4
    for (int it = 0; it < 16; ++it) {
        const int lin = it * 256 + threadIdx.x;
        const int r = lin >> 6, c = lin & 63;
        u16 h, l; split2(t[c][r], h, l);
        oh[(size_t)(n0 + r) * D_ + k0 + c] = h;
        ol[(size_t)(n0 + r) * D_ + k0 + c] = l;
    }
}

// ---------------------------------------------------------------------------
// Fused split-bf16 GEMM (+ optional adjacency GEMM phase).
// Phase-1 LDS tile: 128 rows x 8 chunks(16B); logical chunk q = half*4+kk
// stored at physical chunk p = q ^ (row&7)  (XOR pre-applied on GLOBAL src).
// MODE 0: store relu(H) split hi/lo row-major.
// MODE 1: phase 2 in-LDS: out = relu((adj[b]@H)*invden + bias) + X_in.
template<int MODE>
__global__ __launch_bounds__(256)
void gemm_fused(const u16* __restrict__ Ah, const u16* __restrict__ Al,
                const u16* __restrict__ Bh, const u16* __restrict__ Bl,
                const u16* __restrict__ ADJ, const float* __restrict__ invden,
                const float* __restrict__ bias,
                u16* __restrict__ Oh, u16* __restrict__ Ol) {
    __shared__ u16 lds[2][16384];   // buf: A tile 8192 u16 | B tile 8192 u16
    const int tid  = threadIdx.x;
    const int lane = tid & 63, w = tid >> 6;
    const int wr = w >> 1, wc = w & 1;
    const int lr = lane & 15, lh = lane >> 4;

    int bid = blockIdx.x;
    bid = (bid & 7) * 48 + (bid >> 3);      // XCD swizzle, 384 % 8 == 0 (bijective)
    const int bnb = bid % 6, bmb = bid / 6;
    const int bm = bmb * 128, bn = bnb * 128;

    // --- per-wave staging setup (interleaved + swizzled tile) ---
    const int tile = w >> 1;                 // 0 = A, 1 = B
    const int halfrows = (w & 1) * 64;
    const int lr3 = lane >> 3;               // row-within-8
    const int q = (lane & 7) ^ lr3;          // logical chunk for this lane
    const u16* sbase = (q & 4) ? (tile ? Bl : Al) : (tile ? Bh : Ah);
    const int rowbase = (tile ? bn : bm) + halfrows;
    const u16* gstage = sbase + (size_t)(rowbase + lr3) * 768 + (q & 3) * 8;
    const int ldsoff = tile * 8192 + halfrows * 64;

    f32x4 acc[4][4];
    #pragma unroll
    for (int i = 0; i < 4; ++i)
        #pragma unroll
        for (int j = 0; j < 4; ++j)
            acc[i][j] = (f32x4){0.f, 0.f, 0.f, 0.f};

    // prologue: stage K-tile 0 into buf0
    #pragma unroll
    for (int i = 0; i < 8; ++i)
        gload_lds16(gstage + (size_t)(i * 8) * 768, &lds[0][ldsoff + i * 512]);

    const int r7 = lr & 7;                   // row&7 for fragment rows
    const int pAhi = (lh ^ r7) << 3;         // physical chunk offsets (u16)
    const int pAlo = ((4 | lh) ^ r7) << 3;

    for (int t = 0; t < 24; ++t) {
        if (t < 23) {
            const u16* gs = gstage + (size_t)(t + 1) * 32;
            u16* sd = &lds[(t + 1) & 1][ldsoff];
            #pragma unroll
            for (int i = 0; i < 8; ++i)
                gload_lds16(gs + (size_t)(i * 8) * 768, sd + i * 512);
            asm volatile("s_waitcnt vmcnt(8)" ::: "memory");
        } else if (MODE == 1) {
            // stage adj[b] (128x128 bf16, [n][k]) into buf0, swizzled via src.
            const u16* adjb = ADJ + (size_t)bmb * (N_ * N_);
            #pragma unroll
            for (int i = 0; i < 8; ++i) {
                const int n = w * 32 + i * 4 + lh;
                gload_lds16(adjb + (size_t)n * 128 + ((lr ^ (n & 7)) << 3),
                            &lds[0][w * 4096 + i * 512]);
            }
            asm volatile("s_waitcnt vmcnt(8)" ::: "memory");
        } else {
            asm volatile("s_waitcnt vmcnt(0)" ::: "memory");
        }
        __builtin_amdgcn_s_barrier();
        __builtin_amdgcn_sched_barrier(0);

        const u16* L = lds[t & 1];
        short8 ah[4], al[4], bh4[4], bl4[4];
        #pragma unroll
        for (int f = 0; f < 4; ++f) {
            const int ra = (wr * 64 + f * 16 + lr) * 64;
            const int rb = 8192 + (wc * 64 + f * 16 + lr) * 64;
            ah[f]  = *(const short8*)&L[ra + pAhi];
            al[f]  = *(const short8*)&L[ra + pAlo];
            bh4[f] = *(const short8*)&L[rb + pAhi];
            bl4[f] = *(const short8*)&L[rb + pAlo];
        }
        #pragma unroll
        for (int mf = 0; mf < 4; ++mf)
            #pragma unroll
            for (int nf = 0; nf < 4; ++nf) {
                acc[mf][nf] = __builtin_amdgcn_mfma_f32_16x16x32_bf16(ah[mf], bh4[nf], acc[mf][nf], 0, 0, 0);
                acc[mf][nf] = __builtin_amdgcn_mfma_f32_16x16x32_bf16(ah[mf], bl4[nf], acc[mf][nf], 0, 0, 0);
                acc[mf][nf] = __builtin_amdgcn_mfma_f32_16x16x32_bf16(al[mf], bh4[nf], acc[mf][nf], 0, 0, 0);
            }
        asm volatile("s_waitcnt lgkmcnt(0)" ::: "memory");
        __builtin_amdgcn_s_barrier();
    }

    if (MODE == 0) {
        #pragma unroll
        for (int mf = 0; mf < 4; ++mf)
            #pragma unroll
            for (int r = 0; r < 4; ++r) {
                const int row = bm + wr * 64 + mf * 16 + lh * 4 + r;
                #pragma unroll
                for (int nf = 0; nf < 4; ++nf) {
                    const int c = bn + wc * 64 + nf * 16 + lr;
                    const float v = fmaxf(acc[mf][nf][r], 0.f);
                    u16 h, l; split2(v, h, l);
                    const size_t gi = (size_t)row * 768 + c;
                    Oh[gi] = h; Ol[gi] = l;
                }
            }
        return;
    }

    // ---------------- MODE 1: phase 2 (adjacency GEMM in-LDS) ----------------
    asm volatile("s_waitcnt vmcnt(0)" ::: "memory");   // adj staged
    __builtin_amdgcn_s_barrier();
    __builtin_amdgcn_sched_barrier(0);

    u16* hwT = lds[1];             // H^T tile [c 128][k 128], XOR-swizzled slots
    const u16* adjL = lds[0];      // adj tile [n 128][k 128], XOR-swizzled slots

    // write HI halves of H^T; keep LO in registers
    u16x4 lv[4][4];
    #pragma unroll
    for (int mf = 0; mf < 4; ++mf) {
        const int node0 = wr * 64 + mf * 16 + lh * 4;
        #pragma unroll
        for (int nf = 0; nf < 4; ++nf) {
            const int c = wc * 64 + nf * 16 + lr;
            u16x4 hv;
            #pragma unroll
            for (int r = 0; r < 4; ++r) {
                u16 h, l; split2(acc[mf][nf][r], h, l);
                hv[r] = h; lv[mf][nf][r] = l;
            }
            *(u16x4*)&hwT[c * 128 + (((node0 >> 3) ^ (c & 7)) << 3) + (node0 & 7)] = hv;
        }
    }
    asm volatile("s_waitcnt lgkmcnt(0)" ::: "memory");
    __builtin_amdgcn_s_barrier();
    __builtin_amdgcn_sched_barrier(0);

    f32x4 acc2[4][4];
    #pragma unroll
    for (int i = 0; i < 4; ++i)
        #pragma unroll
        for (int j = 0; j < 4; ++j)
            acc2[i][j] = (f32x4){0.f, 0.f, 0.f, 0.f};

    #pragma unroll
    for (int pass = 0; pass < 2; ++pass) {
        if (pass == 1) {
            #pragma unroll
            for (int mf = 0; mf < 4; ++mf) {
                const int node0 = wr * 64 + mf * 16 + lh * 4;
                #pragma unroll
                for (int nf = 0; nf < 4; ++nf) {
                    const int c = wc * 64 + nf * 16 + lr;
                    *(u16x4*)&hwT[c * 128 + (((node0 >> 3) ^ (c & 7)) << 3) + (node0 & 7)] = lv[mf][nf];
                }
            }
            asm volatile("s_waitcnt lgkmcnt(0)" ::: "memory");
            __builtin_amdgcn_s_barrier();
            __builtin_amdgcn_sched_barrier(0);
        }
        #pragma unroll
        for (int ks = 0; ks < 4; ++ks) {
            short8 af[4], bf[4];
            #pragma unroll
            for (int f = 0; f < 4; ++f) {
                const int node = wr * 64 + f * 16 + lr;
                af[f] = *(const short8*)&adjL[node * 128 + ((((ks << 2) | lh) ^ (node & 7)) << 3)];
                const int c = wc * 64 + f * 16 + lr;
                bf[f] = *(const short8*)&hwT[c * 128 + ((((ks << 2) | lh) ^ (c & 7)) << 3)];
            }
            #pragma unroll
            for (int mf = 0; mf < 4; ++mf)
                #pragma unroll
                for (int nf = 0; nf < 4; ++nf)
                    acc2[mf][nf] = __builtin_amdgcn_mfma_f32_16x16x32_bf16(af[mf], bf[nf], acc2[mf][nf], 0, 0, 0);
        }
        if (pass == 0) {
            asm volatile("s_waitcnt lgkmcnt(0)" ::: "memory");
            __builtin_amdgcn_s_barrier();
            __builtin_amdgcn_sched_barrier(0);
        }
    }

    // epilogue: out = relu(acc2*inv + bias) + X_in; split; store
    const int b = bmb;
    #pragma unroll
    for (int mf = 0; mf < 4; ++mf)
        #pragma unroll
        for (int r = 0; r < 4; ++r) {
            const int node = wr * 64 + mf * 16 + lh * 4 + r;
            const float inv = invden[b * N_ + node];
            const size_t rowbase2 = (size_t)(b * N_ + node) * 768 + bn;
            #pragma unroll
            for (int nf = 0; nf < 4; ++nf) {
                const int c = wc * 64 + nf * 16 + lr;
                float v = fmaxf(acc2[mf][nf][r] * inv + bias[bn + c], 0.f);
                const size_t gi = rowbase2 + c;
                v += bf2f(Ah[gi]) + bf2f(Al[gi]);   // residual = A-source
                u16 h, l; split2(v, h, l);
                Oh[gi] = h; Ol[gi] = l;
            }
        }
}

// ---------------------------------------------------------------------------
__global__ __launch_bounds__(192)
void gcn_target_kernel(const u16* __restrict__ Xh, const u16* __restrict__ Xl,
                       const int* __restrict__ gspan, float* __restrict__ gt) {
    const int b = blockIdx.x;
    const int s = gspan[b * 2 + 0];
    const int e = gspan[b * 2 + 1];
    const int d4 = threadIdx.x;
    float4 acc = make_float4(0.f, 0.f, 0.f, 0.f);
    for (int n = s; n < e; ++n) {
        const size_t base = (size_t)(b * N_ + n) * D_ + d4 * 4;
        const u16x4 h = *(const u16x4*)(Xh + base);
        const u16x4 l = *(const u16x4*)(Xl + base);
        acc.x += bf2f(h[0]) + bf2f(l[0]);
        acc.y += bf2f(h[1]) + bf2f(l[1]);
        acc.z += bf2f(h[2]) + bf2f(l[2]);
        acc.w += bf2f(h[3]) + bf2f(l[3]);
    }
    reinterpret_cast<float4*>(gt + (size_t)b * D_)[d4] = acc;
}

// ---------------------------------------------------------------------------
__global__ __launch_bounds__(256)
void head_kernel(const float* __restrict__ tmax, const float* __restrict__ gt,
                 const float* __restrict__ fcW, const float* __restrict__ fcb,
                 float* __restrict__ out) {
    const int b = blockIdx.x;
    const int t = threadIdx.x;
    float p0 = 0.f, p1 = 0.f, p2 = 0.f;
    for (int i = t; i < 2 * D_; i += 256) {
        const float v = (i < D_) ? tmax[(size_t)b * D_ + i] : gt[(size_t)b * D_ + i - D_];
        p0 += v * fcW[i * 3 + 0];
        p1 += v * fcW[i * 3 + 1];
        p2 += v * fcW[i * 3 + 2];
    }
    #pragma unroll
    for (int off = 32; off; off >>= 1) {
        p0 += __shfl_down(p0, off, 64);
        p1 += __shfl_down(p1, off, 64);
        p2 += __shfl_down(p2, off, 64);
    }
    __shared__ float red[4][3];
    const int wv = t >> 6;
    if ((t & 63) == 0) { red[wv][0] = p0; red[wv][1] = p1; red[wv][2] = p2; }
    __syncthreads();
    if (t == 0) {
        #pragma unroll
        for (int o = 0; o < 3; ++o) {
            const float s = red[0][o] + red[1][o] + red[2][o] + red[3][o] + fcb[o];
            out[b * 3 + o] = tanhf(s);
        }
    }
}

// ---------------------------------------------------------------------------
extern "C" void kernel_launch(void* const* d_in, const int* in_sizes, int n_in,
                              void* d_out, int out_size, void* d_ws, size_t ws_size,
                              hipStream_t stream) {
    const float* se   = (const float*)d_in[0];
    const float* dg   = (const float*)d_in[1];
    const float* dg1  = (const float*)d_in[2];
    const float* Wp   = (const float*)d_in[3];
    const float* Wg[3] = {(const float*)d_in[4], (const float*)d_in[6], (const float*)d_in[8]};
    const float* bg[3] = {(const float*)d_in[5], (const float*)d_in[7], (const float*)d_in[9]};
    const float* fcW  = (const float*)d_in[10];
    const float* fcb  = (const float*)d_in[11];
    const int*   tspan  = (const int*)d_in[12];
    const int*   nspans = (const int*)d_in[13];
    const int*   gspan  = (const int*)d_in[14];
    float* out = (float*)d_out;

    // workspace layout (u16 units unless noted)
    u16* us   = (u16*)d_ws;
    u16* X0h  = us;                        // 8192*768 each
    u16* X0l  = X0h + 6291456;
    u16* X1h  = X0l + 6291456;
    u16* X1l  = X1h + 6291456;
    u16* TH   = X1l + 6291456;             // tmps hi/lo
    u16* TL   = TH  + 6291456;
    u16* WTh  = TL  + 6291456;             // 4*768*768
    u16* WTl  = WTh + 2359296;
    u16* ADJ  = WTl + 2359296;             // 64*128*128
    float* INV = (float*)(ADJ + 1048576);  // 8192
    float* TMX = INV + 8192;               // 64*768
    float* GT  = TMX + 49152;              // 64*768

    // Stage A: ragged prep
    span_split_kernel<<<B_ * N_, 192, 0, stream>>>(se, nspans, TH, TL);
    target_max_kernel<<<B_, 192, 0, stream>>>(se, tspan, TMX);
    adj_kernel<<<B_ * N_, 128, 0, stream>>>(dg, dg1, ADJ, INV);
    wsplit_kernel<<<dim3(12, 12, 4), 256, 0, stream>>>(Wp, Wg[0], Wg[1], Wg[2], WTh, WTl);

    // Stage B: X0 = relu(tmps @ W_proj)
    gemm_fused<0><<<384, 256, 0, stream>>>(TH, TL, WTh, WTl,
                                           nullptr, nullptr, nullptr, X0h, X0l);

    // Stage C: 3 fused GCN layers (ping-pong X0 <-> X1)
    const u16* inh[3] = {X0h, X1h, X0h};
    const u16* inl[3] = {X0l, X1l, X0l};
    u16* outh[3] = {X1h, X0h, X1h};
    u16* outl[3] = {X1l, X0l, X1l};
    for (int l = 0; l < 3; ++l) {
        const size_t wo = (size_t)(l + 1) * D_ * D_;
        gemm_fused<1><<<384, 256, 0, stream>>>(inh[l], inl[l], WTh + wo, WTl + wo,
                                               ADJ, INV, bg[l], outh[l], outl[l]);
    }

    // Stage D: ragged node-span sum + head (final X lives in X1)
    gcn_target_kernel<<<B_, 192, 0, stream>>>(X1h, X1l, gspan, GT);
    head_kernel<<<B_, 256, 0, stream>>>(TMX, GT, fcW, fcb, out);
}

// Round 5
// 189.446 us; speedup vs baseline: 3.6561x; 1.0571x over previous
//
#include <hip/hip_runtime.h>
#include <float.h>
#include <math.h>

typedef __attribute__((ext_vector_type(8))) short short8;
typedef __attribute__((ext_vector_type(4))) float f32x4;
typedef __attribute__((ext_vector_type(4))) unsigned short u16x4;
typedef unsigned short u16;
typedef unsigned int u32;

constexpr int B_ = 64, S_ = 512, N_ = 128, D_ = 768;

// ---------------------------------------------------------------------------
__device__ inline u16 bf16_rne(float x) {
    u32 u = __builtin_bit_cast(u32, x);
    u += 0x7FFFu + ((u >> 16) & 1u);
    return (u16)(u >> 16);
}
__device__ inline float bf2f(u16 h) {
    u32 u = ((u32)h) << 16;
    return __builtin_bit_cast(float, u);
}
__device__ inline void split2(float x, u16& h, u16& l) {
    h = bf16_rne(x);
    l = bf16_rne(x - bf2f(h));
}

__device__ inline void gload_lds16(const u16* g, u16* s) {
    __builtin_amdgcn_global_load_lds(
        (const __attribute__((address_space(1))) u32*)g,
        (__attribute__((address_space(3))) u32*)s, 16, 0, 0);
}

// ---------------------------------------------------------------------------
__global__ __launch_bounds__(192)
void span_split_kernel(const float* __restrict__ se, const int* __restrict__ spans,
                       u16* __restrict__ th, u16* __restrict__ tl) {
    const int bn = blockIdx.x;
    const int b  = bn >> 7;
    const int s  = spans[bn * 2 + 0];
    const int e  = spans[bn * 2 + 1];
    const float* base = se + (size_t)b * S_ * D_;
    const int d4 = threadIdx.x;
    float4 acc = make_float4(0.f, 0.f, 0.f, 0.f);
    for (int r = s + 1; r <= e; ++r) {
        const float4 v = reinterpret_cast<const float4*>(base + (size_t)r * D_)[d4];
        acc.x += v.x; acc.y += v.y; acc.z += v.z; acc.w += v.w;
    }
    u16x4 hv, lv;
    u16 hh, ll;
    split2(acc.x, hh, ll); hv[0] = hh; lv[0] = ll;
    split2(acc.y, hh, ll); hv[1] = hh; lv[1] = ll;
    split2(acc.z, hh, ll); hv[2] = hh; lv[2] = ll;
    split2(acc.w, hh, ll); hv[3] = hh; lv[3] = ll;
    *(u16x4*)(th + (size_t)bn * D_ + d4 * 4) = hv;
    *(u16x4*)(tl + (size_t)bn * D_ + d4 * 4) = lv;
}

// ---------------------------------------------------------------------------
__global__ __launch_bounds__(192)
void target_max_kernel(const float* __restrict__ se, const int* __restrict__ tspan,
                       float* __restrict__ tmax) {
    const int b = blockIdx.x;
    const int s = tspan[b * 2 + 0];
    const int e = tspan[b * 2 + 1];
    const float* base = se + (size_t)b * S_ * D_;
    const int d4 = threadIdx.x;
    float4 m = make_float4(-FLT_MAX, -FLT_MAX, -FLT_MAX, -FLT_MAX);
    for (int r = s; r < e; ++r) {
        const float4 v = reinterpret_cast<const float4*>(base + (size_t)r * D_)[d4];
        m.x = fmaxf(m.x, v.x); m.y = fmaxf(m.y, v.y);
        m.z = fmaxf(m.z, v.z); m.w = fmaxf(m.w, v.w);
    }
    reinterpret_cast<float4*>(tmax + (size_t)b * D_)[d4] = m;
}

// ---------------------------------------------------------------------------
// adj = clamp(dg+dg1,1) -> bf16 (exact {0,1}) [b][n][k]; invden = 1/(rowsum+1e-7)
__global__ __launch_bounds__(128)
void adj_kernel(const float* __restrict__ dg, const float* __restrict__ dg1,
                u16* __restrict__ adj, float* __restrict__ invden) {
    const int row = blockIdx.x;
    const int t   = threadIdx.x;
    const size_t idx = (size_t)row * N_ + t;
    float a = dg[idx] + dg1[idx];
    a = (a >= 1.f) ? 1.f : a;
    adj[idx] = bf16_rne(a);
    float w = a;
    #pragma unroll
    for (int off = 32; off; off >>= 1) w += __shfl_down(w, off, 64);
    __shared__ float ssum[2];
    if ((t & 63) == 0) ssum[t >> 6] = w;
    __syncthreads();
    if (t == 0) invden[row] = 1.f / (ssum[0] + ssum[1] + 1e-7f);
}

// ---------------------------------------------------------------------------
// Weights: W[k][n] (768x768) -> WT[n][k] split bf16 hi/lo. blockIdx.z = matrix.
__global__ __launch_bounds__(256)
void wsplit_kernel(const float* __restrict__ W0, const float* __restrict__ W1,
                   const float* __restrict__ W2, const float* __restrict__ W3,
                   u16* __restrict__ wth, u16* __restrict__ wtl) {
    __shared__ float t[64][65];
    const int mi = blockIdx.z;
    const float* W = (mi == 0) ? W0 : (mi == 1) ? W1 : (mi == 2) ? W2 : W3;
    const int k0 = blockIdx.y * 64, n0 = blockIdx.x * 64;
    #pragma unroll 4
    for (int it = 0; it < 16; ++it) {
        const int lin = it * 256 + threadIdx.x;
        const int r = lin >> 6, c = lin & 63;
        t[r][c] = W[(size_t)(k0 + r) * D_ + n0 + c];
    }
    __syncthreads();
    u16* oh = wth + (size_t)mi * D_ * D_;
    u16* ol = wtl + (size_t)mi * D_ * D_;
    #pragma unroll 4
    for (int it = 0; it < 16; ++it) {
        const int lin = it * 256 + threadIdx.x;
        const int r = lin >> 6, c = lin & 63;
        u16 h, l; split2(t[c][r], h, l);
        oh[(size_t)(n0 + r) * D_ + k0 + c] = h;
        ol[(size_t)(n0 + r) * D_ + k0 + c] = l;
    }
}

// ---------------------------------------------------------------------------
// Fused split-bf16 GEMM, 128x96 tile, 512-block balanced grid (2/CU exact).
// LDS buf (14336 u16 = 28KB): A tile 128x(8x16B chunks) | B tile 96x(8 chunks),
// hi/lo interleaved, chunk p = q ^ (row&7) (XOR pre-applied on global source).
// MODE 0: store relu(H) split hi/lo row-major.
// MODE 1: phase 2 in-LDS: out = relu((adj[b]@H)*invden + bias) + X_in.
//   adj (128x128, 16 chunks/row, p = q ^ (node&7)) spans lds[0..16384);
//   hwT (H^T [c 96][k 128]) at lds[16384..28672).
template<int MODE>
__global__ __launch_bounds__(256, 2)
void gemm_fused(const u16* __restrict__ Ah, const u16* __restrict__ Al,
                const u16* __restrict__ Bh, const u16* __restrict__ Bl,
                const u16* __restrict__ ADJ, const float* __restrict__ invden,
                const float* __restrict__ bias,
                u16* __restrict__ Oh, u16* __restrict__ Ol) {
    __shared__ u16 lds[28672];
    const int tid  = threadIdx.x;
    const int lane = tid & 63, w = tid >> 6;
    const int wr = w >> 1, wc = w & 1;
    const int lr = lane & 15, lh = lane >> 4;

    int bid = blockIdx.x;
    bid = (bid & 7) * 64 + (bid >> 3);      // XCD swizzle, 512 % 8 == 0 (bijective)
    const int bnb = bid & 7, bmb = bid >> 3;
    const int bm = bmb * 128, bn = bnb * 96;

    // --- staging lane constants (28 groups x 8 rows x 8 chunks; 7 per wave) ---
    const int lr3 = lane >> 3;               // row within 8-row group
    const int q   = (lane & 7) ^ lr3;        // logical chunk for this lane
    const u16* aSrc = (q & 4) ? Al : Ah;
    const u16* bSrc = (q & 4) ? Bl : Bh;
    const int qk = (q & 3) * 8;

    auto stage_step = [&](int t, u16* buf) {
        const int k0 = t * 32 + qk;
        #pragma unroll
        for (int i = 0; i < 7; ++i) {
            const int g = w * 7 + i;
            const u16* src = (g < 16)
                ? aSrc + (size_t)(bm + g * 8 + lr3) * 768 + k0
                : bSrc + (size_t)(bn + (g - 16) * 8 + lr3) * 768 + k0;
            gload_lds16(src, buf + g * 512);
        }
    };

    // adj staging lane constants (groups of 4 nodes; 16-chunk rows)
    const int anl = lane >> 4;               // node within group of 4
    const int ap  = lane & 15;               // physical chunk

    f32x4 acc[4][3];
    #pragma unroll
    for (int i = 0; i < 4; ++i)
        #pragma unroll
        for (int j = 0; j < 3; ++j)
            acc[i][j] = (f32x4){0.f, 0.f, 0.f, 0.f};

    stage_step(0, lds);

    const int r7 = lr & 7;
    const int pHi = (lh ^ r7) << 3;
    const int pLo = ((4 | lh) ^ r7) << 3;

    for (int t = 0; t < 24; ++t) {
        if (t < 23) {
            stage_step(t + 1, lds + ((t + 1) & 1) * 14336);
            asm volatile("s_waitcnt vmcnt(7)" ::: "memory");
        } else if (MODE == 1) {
            // stage adj part0 (nodes 0..111) into lds[0..14336) (buf0, free now)
            const u16* adjb = ADJ + (size_t)bmb * (N_ * N_);
            #pragma unroll
            for (int i = 0; i < 7; ++i) {
                const int j = w * 7 + i;
                const int node = j * 4 + anl;
                gload_lds16(adjb + (size_t)node * 128 + ((ap ^ (node & 7)) << 3),
                            lds + j * 512);
            }
            asm volatile("s_waitcnt vmcnt(7)" ::: "memory");
        } else {
            asm volatile("s_waitcnt vmcnt(0)" ::: "memory");
        }
        __builtin_amdgcn_s_barrier();
        __builtin_amdgcn_sched_barrier(0);

        const u16* L = lds + (t & 1) * 14336;
        short8 ah[4], al[4], bh4[3], bl4[3];
        #pragma unroll
        for (int f = 0; f < 4; ++f) {
            const int ra = (wr * 64 + f * 16 + lr) * 64;
            ah[f] = *(const short8*)&L[ra + pHi];
            al[f] = *(const short8*)&L[ra + pLo];
        }
        #pragma unroll
        for (int f = 0; f < 3; ++f) {
            const int rb = 8192 + (wc * 48 + f * 16 + lr) * 64;
            bh4[f] = *(const short8*)&L[rb + pHi];
            bl4[f] = *(const short8*)&L[rb + pLo];
        }
        #pragma unroll
        for (int mf = 0; mf < 4; ++mf)
            #pragma unroll
            for (int nf = 0; nf < 3; ++nf) {
                acc[mf][nf] = __builtin_amdgcn_mfma_f32_16x16x32_bf16(ah[mf], bh4[nf], acc[mf][nf], 0, 0, 0);
                acc[mf][nf] = __builtin_amdgcn_mfma_f32_16x16x32_bf16(ah[mf], bl4[nf], acc[mf][nf], 0, 0, 0);
                acc[mf][nf] = __builtin_amdgcn_mfma_f32_16x16x32_bf16(al[mf], bh4[nf], acc[mf][nf], 0, 0, 0);
            }
        asm volatile("s_waitcnt lgkmcnt(0)" ::: "memory");
        __builtin_amdgcn_s_barrier();
    }

    if (MODE == 0) {
        #pragma unroll
        for (int mf = 0; mf < 4; ++mf)
            #pragma unroll
            for (int r = 0; r < 4; ++r) {
                const int row = bm + wr * 64 + mf * 16 + lh * 4 + r;
                #pragma unroll
                for (int nf = 0; nf < 3; ++nf) {
                    const int c = bn + wc * 48 + nf * 16 + lr;
                    const float v = fmaxf(acc[mf][nf][r], 0.f);
                    u16 h, l; split2(v, h, l);
                    const size_t gi = (size_t)row * 768 + c;
                    Oh[gi] = h; Ol[gi] = l;
                }
            }
        return;
    }

    // ---------------- MODE 1: phase 2 (adjacency GEMM in-LDS) ----------------
    {   // stage adj part1 (nodes 112..127) into lds[14336..16384)
        const u16* adjb = ADJ + (size_t)bmb * (N_ * N_);
        const int j = 28 + w;
        const int node = j * 4 + anl;
        gload_lds16(adjb + (size_t)node * 128 + ((ap ^ (node & 7)) << 3),
                    lds + j * 512);
    }
    asm volatile("s_waitcnt vmcnt(0)" ::: "memory");
    __builtin_amdgcn_s_barrier();
    __builtin_amdgcn_sched_barrier(0);

    u16* hwT = lds + 16384;        // H^T tile [c 96][k 128], 16 chunks swizzled

    // write HI halves of H^T; keep LO in registers
    u16x4 lv[4][3];
    #pragma unroll
    for (int mf = 0; mf < 4; ++mf) {
        const int node0 = wr * 64 + mf * 16 + lh * 4;
        #pragma unroll
        for (int nf = 0; nf < 3; ++nf) {
            const int c = wc * 48 + nf * 16 + lr;
            u16x4 hv;
            #pragma unroll
            for (int r = 0; r < 4; ++r) {
                u16 h, l; split2(acc[mf][nf][r], h, l);
                hv[r] = h; lv[mf][nf][r] = l;
            }
            *(u16x4*)&hwT[c * 128 + (((node0 >> 3) ^ (c & 7)) << 3) + (node0 & 7)] = hv;
        }
    }
    asm volatile("s_waitcnt lgkmcnt(0)" ::: "memory");
    __builtin_amdgcn_s_barrier();
    __builtin_amdgcn_sched_barrier(0);

    f32x4 acc2[4][3];
    #pragma unroll
    for (int i = 0; i < 4; ++i)
        #pragma unroll
        for (int j = 0; j < 3; ++j)
            acc2[i][j] = (f32x4){0.f, 0.f, 0.f, 0.f};

    #pragma unroll
    for (int pass = 0; pass < 2; ++pass) {
        if (pass == 1) {
            #pragma unroll
            for (int mf = 0; mf < 4; ++mf) {
                const int node0 = wr * 64 + mf * 16 + lh * 4;
                #pragma unroll
                for (int nf = 0; nf < 3; ++nf) {
                    const int c = wc * 48 + nf * 16 + lr;
                    *(u16x4*)&hwT[c * 128 + (((node0 >> 3) ^ (c & 7)) << 3) + (node0 & 7)] = lv[mf][nf];
                }
            }
            asm volatile("s_waitcnt lgkmcnt(0)" ::: "memory");
            __builtin_amdgcn_s_barrier();
            __builtin_amdgcn_sched_barrier(0);
        }
        #pragma unroll
        for (int ks = 0; ks < 4; ++ks) {
            short8 af[4], bf[3];
            #pragma unroll
            for (int f = 0; f < 4; ++f) {
                const int node = wr * 64 + f * 16 + lr;
                af[f] = *(const short8*)&lds[node * 128 + (((ks * 4 + lh) ^ (node & 7)) << 3)];
            }
            #pragma unroll
            for (int f = 0; f < 3; ++f) {
                const int c = wc * 48 + f * 16 + lr;
                bf[f] = *(const short8*)&hwT[c * 128 + (((ks * 4 + lh) ^ (c & 7)) << 3)];
            }
            #pragma unroll
            for (int mf = 0; mf < 4; ++mf)
                #pragma unroll
                for (int nf = 0; nf < 3; ++nf)
                    acc2[mf][nf] = __builtin_amdgcn_mfma_f32_16x16x32_bf16(af[mf], bf[nf], acc2[mf][nf], 0, 0, 0);
        }
        if (pass == 0) {
            asm volatile("s_waitcnt lgkmcnt(0)" ::: "memory");
            __builtin_amdgcn_s_barrier();
            __builtin_amdgcn_sched_barrier(0);
        }
    }

    // epilogue: out = relu(acc2*inv + bias) + X_in; split; store
    #pragma unroll
    for (int mf = 0; mf < 4; ++mf)
        #pragma unroll
        for (int r = 0; r < 4; ++r) {
            const int node = wr * 64 + mf * 16 + lh * 4 + r;
            const float inv = invden[bmb * N_ + node];
            const size_t rowbase = (size_t)(bmb * N_ + node) * 768 + bn;
            #pragma unroll
            for (int nf = 0; nf < 3; ++nf) {
                const int c = wc * 48 + nf * 16 + lr;
                float v = fmaxf(acc2[mf][nf][r] * inv + bias[bn + c], 0.f);
                const size_t gi = rowbase + c;
                v += bf2f(Ah[gi]) + bf2f(Al[gi]);   // residual = A-source
                u16 h, l; split2(v, h, l);
                Oh[gi] = h; Ol[gi] = l;
            }
        }
}

// ---------------------------------------------------------------------------
__global__ __launch_bounds__(192)
void gcn_target_kernel(const u16* __restrict__ Xh, const u16* __restrict__ Xl,
                       const int* __restrict__ gspan, float* __restrict__ gt) {
    const int b = blockIdx.x;
    const int s = gspan[b * 2 + 0];
    const int e = gspan[b * 2 + 1];
    const int d4 = threadIdx.x;
    float4 acc = make_float4(0.f, 0.f, 0.f, 0.f);
    for (int n = s; n < e; ++n) {
        const size_t base = (size_t)(b * N_ + n) * D_ + d4 * 4;
        const u16x4 h = *(const u16x4*)(Xh + base);
        const u16x4 l = *(const u16x4*)(Xl + base);
        acc.x += bf2f(h[0]) + bf2f(l[0]);
        acc.y += bf2f(h[1]) + bf2f(l[1]);
        acc.z += bf2f(h[2]) + bf2f(l[2]);
        acc.w += bf2f(h[3]) + bf2f(l[3]);
    }
    reinterpret_cast<float4*>(gt + (size_t)b * D_)[d4] = acc;
}

// ---------------------------------------------------------------------------
__global__ __launch_bounds__(256)
void head_kernel(const float* __restrict__ tmax, const float* __restrict__ gt,
                 const float* __restrict__ fcW, const float* __restrict__ fcb,
                 float* __restrict__ out) {
    const int b = blockIdx.x;
    const int t = threadIdx.x;
    float p0 = 0.f, p1 = 0.f, p2 = 0.f;
    for (int i = t; i < 2 * D_; i += 256) {
        const float v = (i < D_) ? tmax[(size_t)b * D_ + i] : gt[(size_t)b * D_ + i - D_];
        p0 += v * fcW[i * 3 + 0];
        p1 += v * fcW[i * 3 + 1];
        p2 += v * fcW[i * 3 + 2];
    }
    #pragma unroll
    for (int off = 32; off; off >>= 1) {
        p0 += __shfl_down(p0, off, 64);
        p1 += __shfl_down(p1, off, 64);
        p2 += __shfl_down(p2, off, 64);
    }
    __shared__ float red[4][3];
    const int wv = t >> 6;
    if ((t & 63) == 0) { red[wv][0] = p0; red[wv][1] = p1; red[wv][2] = p2; }
    __syncthreads();
    if (t == 0) {
        #pragma unroll
        for (int o = 0; o < 3; ++o) {
            const float s = red[0][o] + red[1][o] + red[2][o] + red[3][o] + fcb[o];
            out[b * 3 + o] = tanhf(s);
        }
    }
}

// ---------------------------------------------------------------------------
extern "C" void kernel_launch(void* const* d_in, const int* in_sizes, int n_in,
                              void* d_out, int out_size, void* d_ws, size_t ws_size,
                              hipStream_t stream) {
    const float* se   = (const float*)d_in[0];
    const float* dg   = (const float*)d_in[1];
    const float* dg1  = (const float*)d_in[2];
    const float* Wp   = (const float*)d_in[3];
    const float* Wg[3] = {(const float*)d_in[4], (const float*)d_in[6], (const float*)d_in[8]};
    const float* bg[3] = {(const float*)d_in[5], (const float*)d_in[7], (const float*)d_in[9]};
    const float* fcW  = (const float*)d_in[10];
    const float* fcb  = (const float*)d_in[11];
    const int*   tspan  = (const int*)d_in[12];
    const int*   nspans = (const int*)d_in[13];
    const int*   gspan  = (const int*)d_in[14];
    float* out = (float*)d_out;

    // workspace layout (u16 units unless noted)
    u16* us   = (u16*)d_ws;
    u16* X0h  = us;                        // 8192*768 each
    u16* X0l  = X0h + 6291456;
    u16* X1h  = X0l + 6291456;
    u16* X1l  = X1h + 6291456;
    u16* TH   = X1l + 6291456;             // tmps hi/lo
    u16* TL   = TH  + 6291456;
    u16* WTh  = TL  + 6291456;             // 4*768*768
    u16* WTl  = WTh + 2359296;
    u16* ADJ  = WTl + 2359296;             // 64*128*128
    float* INV = (float*)(ADJ + 1048576);  // 8192
    float* TMX = INV + 8192;               // 64*768
    float* GT  = TMX + 49152;              // 64*768

    // Stage A: ragged prep
    span_split_kernel<<<B_ * N_, 192, 0, stream>>>(se, nspans, TH, TL);
    target_max_kernel<<<B_, 192, 0, stream>>>(se, tspan, TMX);
    adj_kernel<<<B_ * N_, 128, 0, stream>>>(dg, dg1, ADJ, INV);
    wsplit_kernel<<<dim3(12, 12, 4), 256, 0, stream>>>(Wp, Wg[0], Wg[1], Wg[2], WTh, WTl);

    // Stage B: X0 = relu(tmps @ W_proj)   (512 blocks, 64 row-panels x 8 col-96)
    gemm_fused<0><<<512, 256, 0, stream>>>(TH, TL, WTh, WTl,
                                           nullptr, nullptr, nullptr, X0h, X0l);

    // Stage C: 3 fused GCN layers (ping-pong X0 <-> X1)
    const u16* inh[3] = {X0h, X1h, X0h};
    const u16* inl[3] = {X0l, X1l, X0l};
    u16* outh[3] = {X1h, X0h, X1h};
    u16* outl[3] = {X1l, X0l, X1l};
    for (int l = 0; l < 3; ++l) {
        const size_t wo = (size_t)(l + 1) * D_ * D_;
        gemm_fused<1><<<512, 256, 0, stream>>>(inh[l], inl[l], WTh + wo, WTl + wo,
                                               ADJ, INV, bg[l], outh[l], outl[l]);
    }

    // Stage D: ragged node-span sum + head (final X lives in X1)
    gcn_target_kernel<<<B_, 192, 0, stream>>>(X1h, X1l, gspan, GT);
    head_kernel<<<B_, 256, 0, stream>>>(TMX, GT, fcW, fcb, out);
}